// Round 7
// baseline (249.611 us; speedup 1.0000x reference)
//
#include <hip/hip_runtime.h>
#include <hip/hip_bf16.h>

// Problem: x[4,2048,1024] f32; w_qkv[1024,3072]; w_out[1024,1024]; b_out[1024]
// out[4,2048,1024] f32.  HEADS=16, DH=64, scale=0.125 (folded with log2e into Q).

typedef __attribute__((ext_vector_type(4))) float f32x4;
typedef __attribute__((ext_vector_type(16))) float f32x16;
typedef __attribute__((ext_vector_type(8))) unsigned short u16x8;
typedef __attribute__((ext_vector_type(4))) unsigned short u16x4;
typedef __attribute__((ext_vector_type(4))) unsigned int u32x4;
typedef __attribute__((ext_vector_type(8))) __bf16 bf16x8;

static __device__ __forceinline__ f32x4 mfma_bf16(u16x8 a, u16x8 b, f32x4 c) {
    return __builtin_amdgcn_mfma_f32_16x16x32_bf16(
        __builtin_bit_cast(bf16x8, a), __builtin_bit_cast(bf16x8, b), c, 0, 0, 0);
}
static __device__ __forceinline__ f32x16 mfma32(u16x8 a, u16x8 b, f32x16 c) {
    return __builtin_amdgcn_mfma_f32_32x32x16_bf16(
        __builtin_bit_cast(bf16x8, a), __builtin_bit_cast(bf16x8, b), c, 0, 0, 0);
}

static __device__ __forceinline__ unsigned short f2bf(float f) {
    unsigned int u = __builtin_bit_cast(unsigned int, f);
    u += 0x7fffu + ((u >> 16) & 1u);   // RNE
    return (unsigned short)(u >> 16);
}
static __device__ __forceinline__ unsigned int cvt_pk_bf16(float a, float b) {
    unsigned int r;
    asm("v_cvt_pk_bf16_f32 %0, %1, %2" : "=v"(r) : "v"(a), "v"(b));
    return r;
}
static __device__ __forceinline__ float fexp2(float x) {   // D = 2^S0
    float r;
    asm("v_exp_f32 %0, %1" : "=v"(r) : "v"(x));
    return r;
}
static __device__ __forceinline__ float frcp(float x) {
    float r;
    asm("v_rcp_f32 %0, %1" : "=v"(r) : "v"(x));
    return r;
}
typedef const __attribute__((address_space(1))) unsigned int* gp1_t;
typedef __attribute__((address_space(3))) unsigned int* lp3_t;
static __device__ __forceinline__ void gl_lds16(const void* g, void* l) {
    __builtin_amdgcn_global_load_lds((gp1_t)g, (lp3_t)l, 16, 0, 0);
}

// ---------------- convert x (f32 -> bf16), vectorized ----------------
__global__ void k_cvt(const float* __restrict__ in, unsigned short* __restrict__ out, int n4) {
    int i = blockIdx.x * blockDim.x + threadIdx.x;
    int stride = gridDim.x * blockDim.x;
    for (; i < n4; i += stride) {
        f32x4 v = ((const f32x4*)in)[i];
        u16x4 o;
        #pragma unroll
        for (int j = 0; j < 4; ++j) o[j] = f2bf(v[j]);
        ((u16x4*)out)[i] = o;
    }
}

// ---------------- transpose f32 [R][C] -> bf16 [C][R] ----------------
__global__ void k_transpose(const float* __restrict__ in, unsigned short* __restrict__ out,
                            int R, int C) {
    __shared__ float tile[32][33];
    int c0 = blockIdx.x * 32, r0 = blockIdx.y * 32;
    int tx = threadIdx.x, ty = threadIdx.y;   // block (32,8)
    #pragma unroll
    for (int i = ty; i < 32; i += 8)
        tile[i][tx] = in[(size_t)(r0 + i) * C + c0 + tx];
    __syncthreads();
    #pragma unroll
    for (int i = ty; i < 32; i += 8)
        out[(size_t)(c0 + i) * R + r0 + tx] = f2bf(tile[tx][i]);
}

// ---------------- GEMM: A[8192][1024]bf16 @ BT[N][1024]bf16 ----------------
// 256x256 tile, BK=64, 8 waves (2M x 4N) -> wave tile 128x64 (FLOP/LDS-byte
// 42.7 vs 32 at 64x64 -> LDS-read no longer the cap). Double-buffered LDS,
// stage(t+1) issued at tile start (full-tile lead over its vmcnt(0)), one
// barrier per K-tile so waves drift and overlap MFMA/LDS/VMEM across waves.
__global__ __launch_bounds__(512, 1) void k_gemm(
    const unsigned short* __restrict__ A,
    const unsigned short* __restrict__ BT,
    const float* __restrict__ bias,
    float* __restrict__ outf,
    unsigned short* __restrict__ Qs,
    unsigned short* __restrict__ Ks,
    unsigned short* __restrict__ VTs,
    int mode)
{
    __shared__ unsigned short As[2][256 * 64];
    __shared__ unsigned short Bs[2][256 * 64];
    const int K = 1024;
    const int tid = threadIdx.x, lane = tid & 63, wave = tid >> 6;

    // bijective XCD swizzle (nwg % 8 == 0 in both uses)
    int gx = gridDim.x;
    int nwg = gx * gridDim.y;
    int lin = blockIdx.y * gx + blockIdx.x;
    int virt = (lin & 7) * (nwg >> 3) + (lin >> 3);
    int bx = virt % gx, by = virt / gx;
    const int m0 = by * 256, n0 = bx * 256;

    const int wm = (wave >> 2) * 128, wn = (wave & 3) * 64;
    const int lr = lane & 15, half = lane >> 4;
    const int srow = lane >> 3, sslot = lane & 7;

    // stage K-tile t into buffer buf: A and B each 32KB = 32 chunks of 1KB
    // (8 rows x 8 16B-slots; LDS slot s holds global k-chunk s^(row&7)).
    auto stage = [&](int buf, int t) {
        int k0 = t * 64;
        #pragma unroll
        for (int r = 0; r < 4; ++r) {
            int chunk = r * 8 + wave;
            int row = chunk * 8 + srow;
            int koff = (sslot ^ (row & 7)) * 8;
            gl_lds16(&A[(size_t)(m0 + row) * K + k0 + koff], &As[buf][chunk * 512]);
        }
        #pragma unroll
        for (int r = 0; r < 4; ++r) {
            int chunk = r * 8 + wave;
            int row = chunk * 8 + srow;
            int koff = (sslot ^ (row & 7)) * 8;
            gl_lds16(&BT[(size_t)(n0 + row) * K + k0 + koff], &Bs[buf][chunk * 512]);
        }
    };

    f32x4 acc[8][4] = {};

    stage(0, 0);
    asm volatile("s_waitcnt vmcnt(0)" ::: "memory");
    __builtin_amdgcn_s_barrier();

    for (int t = 0; t < 16; ++t) {
        const int cur = t & 1;
        if (t < 15) stage(cur ^ 1, t + 1);   // full-tile lead before its wait
        const unsigned short* Ab = As[cur];
        const unsigned short* Bb = Bs[cur];

        #pragma unroll
        for (int ks = 0; ks < 2; ++ks) {
            u16x8 bfr[4];
            #pragma unroll
            for (int j = 0; j < 4; ++j) {
                int rb = wn + j * 16 + lr;
                bfr[j] = *(const u16x8*)&Bb[rb * 64 + (((ks * 4 + half) ^ (rb & 7)) * 8)];
            }
            #pragma unroll
            for (int ih = 0; ih < 2; ++ih) {
                u16x8 af[4];
                #pragma unroll
                for (int ii = 0; ii < 4; ++ii) {
                    int ra = wm + (ih * 4 + ii) * 16 + lr;
                    af[ii] = *(const u16x8*)&Ab[ra * 64 + (((ks * 4 + half) ^ (ra & 7)) * 8)];
                }
                __builtin_amdgcn_s_setprio(1);
                #pragma unroll
                for (int ii = 0; ii < 4; ++ii)
                    #pragma unroll
                    for (int j = 0; j < 4; ++j)
                        acc[ih * 4 + ii][j] = mfma_bf16(af[ii], bfr[j], acc[ih * 4 + ii][j]);
                __builtin_amdgcn_s_setprio(0);
            }
        }

        // one boundary per tile: staged loads landed + everyone done reading
        asm volatile("s_waitcnt vmcnt(0) lgkmcnt(0)" ::: "memory");
        __builtin_amdgcn_s_barrier();
    }

    #pragma unroll
    for (int i = 0; i < 8; ++i) {
        #pragma unroll
        for (int j = 0; j < 4; ++j) {
            #pragma unroll
            for (int r = 0; r < 4; ++r) {
                int row = m0 + wm + i * 16 + half * 4 + r;
                int col = n0 + wn + j * 16 + lr;
                float v = acc[i][j][r];
                if (mode == 1) {
                    outf[(size_t)row * 1024 + col] = v + bias[col];
                } else {
                    int part = col >> 10, cj = col & 1023;
                    int h = cj >> 6, d = cj & 63;
                    int b = row >> 11, n = row & 2047;
                    int bh = b * 16 + h;
                    if (part == 0)   // fold 0.125 * log2(e): attn uses p = 2^s
                        Qs[((size_t)bh * 2048 + n) * 64 + d] = f2bf(v * 0.18033688f);
                    else if (part == 1)
                        Ks[((size_t)bh * 2048 + n) * 64 + d] = f2bf(v);
                    else
                        VTs[((size_t)bh * 64 + d) * 2048 + n] = f2bf(v);
                }
            }
        }
    }
}

// ---------------- flash attention: swapped-QK 32x32, 2 q-blocks/wave --------
// grid (8, 64) XCD-swizzled; block 256 = 4 waves; wave owns 64 q-rows (2x32).
// LDS tiles: 32 rows x 256B, 16-slot XOR swizzle (2-way max aliasing = free).
// p = 2^s directly (scale*log2e folded into Q); row sums via ones-MFMA.
__global__ __launch_bounds__(256, 2) void k_attn(
    const unsigned short* __restrict__ Qs,
    const unsigned short* __restrict__ Ks,
    const unsigned short* __restrict__ VTs,
    unsigned short* __restrict__ attn)   // [8192][1024] bf16
{
    __shared__ unsigned short Kt[2][64 * 64];
    __shared__ unsigned short Vt[2][64 * 64];
    const int tid = threadIdx.x, lane = tid & 63, wave = tid >> 6;

    int lin = blockIdx.y * 8 + blockIdx.x;          // 512 wgs, bijective
    int virt = (lin & 7) * 64 + (lin >> 3);
    int bh = virt >> 3;
    int q0 = (virt & 7) * 256 + wave * 64;

    const int lq = lane & 31;
    const int hi = lane >> 5;
    const bool hib = hi != 0;

    const unsigned short* Kbase = Ks + (size_t)bh * 2048 * 64;
    const unsigned short* Vbase = VTs + (size_t)bh * 64 * 2048;

    u16x8 qf0[4], qf1[4];
    {
        const unsigned short* Qr0 = Qs + ((size_t)bh * 2048 + q0 + lq) * 64;
        const unsigned short* Qr1 = Qr0 + 32 * 64;
        #pragma unroll
        for (int kk = 0; kk < 4; ++kk) {
            qf0[kk] = *(const u16x8*)&Qr0[kk * 16 + hi * 8];
            qf1[kk] = *(const u16x8*)&Qr1[kk * 16 + hi * 8];
        }
    }

    const int srow_in = lane >> 4, sslot = lane & 15;
    auto stage = [&](int buf, int j0) {
        #pragma unroll
        for (int c = 0; c < 2; ++c) {
            int chunk = wave * 2 + c;
            int row = chunk * 4 + srow_in;           // 0..31
            int v = sslot ^ (row & 15);
            int high = v >> 3, dsl = (v & 7) * 8;
            gl_lds16(Kbase + (size_t)(j0 + high * 32 + row) * 64 + dsl, &Kt[buf][chunk * 512]);
            gl_lds16(Vbase + (size_t)(high * 32 + row) * 2048 + j0 + dsl, &Vt[buf][chunk * 512]);
        }
    };

    f32x16 o0[2] = {}, o1[2] = {};
    f32x16 osum0 = {}, osum1 = {};
    const u16x8 onesf = {0x3F80, 0x3F80, 0x3F80, 0x3F80, 0x3F80, 0x3F80, 0x3F80, 0x3F80};

    stage(0, 0);
    __syncthreads();
    int cur = 0;

    for (int t = 0; t < 32; ++t) {
        if (t < 31) stage(cur ^ 1, (t + 1) * 64);

        // ---- QK^T: S^T[j][q] in log2 units, both q-blocks share kf ----
        f32x16 sacc0[2] = {}, sacc1[2] = {};
        __builtin_amdgcn_s_setprio(1);
        #pragma unroll
        for (int jb = 0; jb < 2; ++jb) {
            u16x8 kf[4];
            #pragma unroll
            for (int kk = 0; kk < 4; ++kk) {
                int s = (jb * 8 + kk * 2 + hi) ^ (lq & 15);
                kf[kk] = *(const u16x8*)&Kt[cur][lq * 128 + s * 8];
            }
            #pragma unroll
            for (int kk = 0; kk < 4; ++kk) sacc0[jb] = mfma32(kf[kk], qf0[kk], sacc0[jb]);
            #pragma unroll
            for (int kk = 0; kk < 4; ++kk) sacc1[jb] = mfma32(kf[kk], qf1[kk], sacc1[jb]);
        }
        __builtin_amdgcn_s_setprio(0);

        // ---- p = 2^s, pack to bf16 pairs ----
        unsigned int pk0[16], pk1[16];
        #pragma unroll
        for (int jb = 0; jb < 2; ++jb)
            #pragma unroll
            for (int i = 0; i < 8; ++i) {
                pk0[jb * 8 + i] = cvt_pk_bf16(fexp2(sacc0[jb][2 * i]), fexp2(sacc0[jb][2 * i + 1]));
                pk1[jb * 8 + i] = cvt_pk_bf16(fexp2(sacc1[jb][2 * i]), fexp2(sacc1[jb][2 * i + 1]));
            }

        // ---- PV + ones-MFMA row sums ----
        #pragma unroll
        for (int kk = 0; kk < 4; ++kk) {
            const int base = (kk >> 1) * 8 + (kk & 1) * 4;
            unsigned int a0 = pk0[base + 0], a1 = pk0[base + 1], a2 = pk0[base + 2], a3 = pk0[base + 3];
            unsigned int b0 = pk1[base + 0], b1 = pk1[base + 1], b2 = pk1[base + 2], b3 = pk1[base + 3];
            unsigned int sa0 = __shfl_xor(a0, 32), sa1 = __shfl_xor(a1, 32);
            unsigned int sa2 = __shfl_xor(a2, 32), sa3 = __shfl_xor(a3, 32);
            unsigned int sb0 = __shfl_xor(b0, 32), sb1 = __shfl_xor(b1, 32);
            unsigned int sb2 = __shfl_xor(b2, 32), sb3 = __shfl_xor(b3, 32);
            u32x4 w0, w1;
            w0[0] = hib ? sa2 : a0;  w0[1] = hib ? sa3 : a1;
            w0[2] = hib ? a2 : sa0;  w0[3] = hib ? a3 : sa1;
            w1[0] = hib ? sb2 : b0;  w1[1] = hib ? sb3 : b1;
            w1[2] = hib ? b2 : sb0;  w1[3] = hib ? b3 : sb1;
            u16x8 pa0 = __builtin_bit_cast(u16x8, w0);
            u16x8 pa1 = __builtin_bit_cast(u16x8, w1);
            __builtin_amdgcn_s_setprio(1);
            osum0 = mfma32(pa0, onesf, osum0);
            osum1 = mfma32(pa1, onesf, osum1);
            #pragma unroll
            for (int db = 0; db < 2; ++db) {
                int s = (db * 8 + kk * 2 + hi) ^ (lq & 15);
                u16x8 vf = *(const u16x8*)&Vt[cur][lq * 128 + s * 8];
                o0[db] = mfma32(pa0, vf, o0[db]);
                o1[db] = mfma32(pa1, vf, o1[db]);
            }
            __builtin_amdgcn_s_setprio(0);
        }

        __syncthreads();
        cur ^= 1;
    }

    // ---- epilogue: normalize and store ----
    int b = bh >> 4, h = bh & 15;
    #pragma unroll
    for (int r = 0; r < 16; ++r) {
        int qrow = (r & 3) + 8 * (r >> 2) + 4 * hi;
        float i0 = frcp(osum0[r]);
        float i1 = frcp(osum1[r]);
        size_t ro0 = (size_t)(b * 2048 + q0 + qrow) * 1024 + h * 64;
        size_t ro1 = (size_t)(b * 2048 + q0 + 32 + qrow) * 1024 + h * 64;
        attn[ro0 + lq]      = f2bf(o0[0][r] * i0);
        attn[ro0 + 32 + lq] = f2bf(o0[1][r] * i0);
        attn[ro1 + lq]      = f2bf(o1[0][r] * i1);
        attn[ro1 + 32 + lq] = f2bf(o1[1][r] * i1);
    }
}

extern "C" void kernel_launch(void* const* d_in, const int* in_sizes, int n_in,
                              void* d_out, int out_size, void* d_ws, size_t ws_size,
                              hipStream_t stream) {
    const float* x     = (const float*)d_in[0];
    const float* w_qkv = (const float*)d_in[1];
    const float* w_out = (const float*)d_in[2];
    const float* b_out = (const float*)d_in[3];
    float* out = (float*)d_out;

    char* ws = (char*)d_ws;
    size_t off = 0;
    auto alloc = [&](size_t bytes) -> void* {
        void* p = ws + off;
        off += (bytes + 255) & ~(size_t)255;
        return p;
    };
    unsigned short* xb    = (unsigned short*)alloc(8192ull * 1024 * 2);
    unsigned short* wqkvT = (unsigned short*)alloc(3072ull * 1024 * 2);
    unsigned short* woutT = (unsigned short*)alloc(1024ull * 1024 * 2);
    unsigned short* Qs    = (unsigned short*)alloc(64ull * 2048 * 64 * 2);
    unsigned short* Ks    = (unsigned short*)alloc(64ull * 2048 * 64 * 2);
    unsigned short* VTs   = (unsigned short*)alloc(64ull * 2048 * 64 * 2);
    unsigned short* attn  = (unsigned short*)alloc(8192ull * 1024 * 2);
    if (off > ws_size) return;

    k_cvt<<<2048, 256, 0, stream>>>(x, xb, 8192 * 1024 / 4);
    k_transpose<<<dim3(3072 / 32, 1024 / 32), dim3(32, 8), 0, stream>>>(w_qkv, wqkvT, 1024, 3072);
    k_transpose<<<dim3(1024 / 32, 1024 / 32), dim3(32, 8), 0, stream>>>(w_out, woutT, 1024, 1024);
    k_gemm<<<dim3(3072 / 256, 8192 / 256), 512, 0, stream>>>(xb, wqkvT, nullptr, nullptr, Qs, Ks, VTs, 0);
    k_attn<<<dim3(8, 64), 256, 0, stream>>>(Qs, Ks, VTs, attn);
    k_gemm<<<dim3(1024 / 256, 8192 / 256), 512, 0, stream>>>(attn, woutT, b_out, out, nullptr, nullptr, nullptr, 1);
}

// Round 8
// 209.247 us; speedup vs baseline: 1.1929x; 1.1929x over previous
//
#include <hip/hip_runtime.h>
#include <hip/hip_bf16.h>

// Problem: x[4,2048,1024] f32; w_qkv[1024,3072]; w_out[1024,1024]; b_out[1024]
// out[4,2048,1024] f32.  HEADS=16, DH=64, scale=0.125 (folded with log2e into Q).

typedef __attribute__((ext_vector_type(4))) float f32x4;
typedef __attribute__((ext_vector_type(16))) float f32x16;
typedef __attribute__((ext_vector_type(8))) unsigned short u16x8;
typedef __attribute__((ext_vector_type(4))) unsigned short u16x4;
typedef __attribute__((ext_vector_type(4))) unsigned int u32x4;
typedef __attribute__((ext_vector_type(8))) __bf16 bf16x8;

static __device__ __forceinline__ f32x4 mfma_bf16(u16x8 a, u16x8 b, f32x4 c) {
    return __builtin_amdgcn_mfma_f32_16x16x32_bf16(
        __builtin_bit_cast(bf16x8, a), __builtin_bit_cast(bf16x8, b), c, 0, 0, 0);
}
static __device__ __forceinline__ f32x16 mfma32(u16x8 a, u16x8 b, f32x16 c) {
    return __builtin_amdgcn_mfma_f32_32x32x16_bf16(
        __builtin_bit_cast(bf16x8, a), __builtin_bit_cast(bf16x8, b), c, 0, 0, 0);
}

static __device__ __forceinline__ unsigned short f2bf(float f) {
    unsigned int u = __builtin_bit_cast(unsigned int, f);
    u += 0x7fffu + ((u >> 16) & 1u);   // RNE
    return (unsigned short)(u >> 16);
}
static __device__ __forceinline__ unsigned int cvt_pk_bf16(float a, float b) {
    unsigned int r;
    asm("v_cvt_pk_bf16_f32 %0, %1, %2" : "=v"(r) : "v"(a), "v"(b));
    return r;
}
static __device__ __forceinline__ float fexp2(float x) {   // D = 2^S0
    float r;
    asm("v_exp_f32 %0, %1" : "=v"(r) : "v"(x));
    return r;
}
static __device__ __forceinline__ float frcp(float x) {
    float r;
    asm("v_rcp_f32 %0, %1" : "=v"(r) : "v"(x));
    return r;
}
typedef const __attribute__((address_space(1))) unsigned int* gp1_t;
typedef __attribute__((address_space(3))) unsigned int* lp3_t;
static __device__ __forceinline__ void gl_lds16(const void* g, void* l) {
    __builtin_amdgcn_global_load_lds((gp1_t)g, (lp3_t)l, 16, 0, 0);
}

// ---------------- convert x (f32 -> bf16), vectorized ----------------
__global__ void k_cvt(const float* __restrict__ in, unsigned short* __restrict__ out, int n4) {
    int i = blockIdx.x * blockDim.x + threadIdx.x;
    int stride = gridDim.x * blockDim.x;
    for (; i < n4; i += stride) {
        f32x4 v = ((const f32x4*)in)[i];
        u16x4 o;
        #pragma unroll
        for (int j = 0; j < 4; ++j) o[j] = f2bf(v[j]);
        ((u16x4*)out)[i] = o;
    }
}

// ---------------- transpose f32 [R][C] -> bf16 [C][R] ----------------
__global__ void k_transpose(const float* __restrict__ in, unsigned short* __restrict__ out,
                            int R, int C) {
    __shared__ float tile[32][33];
    int c0 = blockIdx.x * 32, r0 = blockIdx.y * 32;
    int tx = threadIdx.x, ty = threadIdx.y;   // block (32,8)
    #pragma unroll
    for (int i = ty; i < 32; i += 8)
        tile[i][tx] = in[(size_t)(r0 + i) * C + c0 + tx];
    __syncthreads();
    #pragma unroll
    for (int i = ty; i < 32; i += 8)
        out[(size_t)(c0 + i) * R + r0 + tx] = f2bf(tile[tx][i]);
}

// ---------------- GEMM1 (QKV): A[8192][1024] @ BT[3072][1024] ----------------
// 256x256 tile, BK=64, 8 waves 2Mx4N -> wave tile 128x64. Double-buffered LDS.
// Per K-tile: burst-stage t+1 (8 gl_lds) -> 4 quadrant phases {ds_read,
// lgkm(0)+SB(0), setprio 16 MFMA} -> vmcnt(0) (cover = full tile) -> barrier.
// Column-major XCD map: each XCD holds <=2 B-panels (1MB, L2-resident).
__global__ __launch_bounds__(512, 2) void k_gemm1(
    const unsigned short* __restrict__ A,
    const unsigned short* __restrict__ BT,
    unsigned short* __restrict__ Qs,
    unsigned short* __restrict__ Ks,
    unsigned short* __restrict__ VTs)
{
    __shared__ unsigned short As[2][256 * 64];
    __shared__ unsigned short Bs[2][256 * 64];
    const int K = 1024;
    const int tid = threadIdx.x, lane = tid & 63, wave = tid >> 6;

    // grid (12, 32); column-major per-XCD tile order
    int lin = blockIdx.y * 12 + blockIdx.x;
    int xcd = lin & 7, idx = lin >> 3;         // idx 0..47
    int virt = xcd * 48 + idx;
    int by = virt & 31, bx = virt >> 5;        // by fast -> same B-panel per XCD
    const int m0 = by * 256, n0 = bx * 256;

    const int wm = (wave >> 2) * 128, wn = (wave & 3) * 64;
    const int lr = lane & 15, half = lane >> 4;
    const int srow = lane >> 3, sslot = lane & 7;

    auto stage = [&](int buf, int t) {
        int k0 = t * 64;
        #pragma unroll
        for (int r = 0; r < 4; ++r) {
            int chunk = r * 8 + wave;
            int row = chunk * 8 + srow;
            int koff = (sslot ^ (row & 7)) * 8;
            gl_lds16(&A[(size_t)(m0 + row) * K + k0 + koff], &As[buf][chunk * 512]);
        }
        #pragma unroll
        for (int r = 0; r < 4; ++r) {
            int chunk = r * 8 + wave;
            int row = chunk * 8 + srow;
            int koff = (sslot ^ (row & 7)) * 8;
            gl_lds16(&BT[(size_t)(n0 + row) * K + k0 + koff], &Bs[buf][chunk * 512]);
        }
    };

    f32x4 acc[8][4] = {};

    stage(0, 0);
    asm volatile("s_waitcnt vmcnt(0)" ::: "memory");
    __builtin_amdgcn_s_barrier();

    for (int t = 0; t < 16; ++t) {
        const int cur = t & 1;
        if (t < 15) stage(cur ^ 1, t + 1);   // burst: full-tile drain cover
        const unsigned short* Ab = As[cur];
        const unsigned short* Bb = Bs[cur];

        u16x8 bfr[4];
        #pragma unroll
        for (int q = 0; q < 4; ++q) {
            const int ks = q >> 1, ih = q & 1;
            if (ih == 0) {
                #pragma unroll
                for (int j = 0; j < 4; ++j) {
                    int rb = wn + j * 16 + lr;
                    bfr[j] = *(const u16x8*)&Bb[rb * 64 + (((ks * 4 + half) ^ (rb & 7)) * 8)];
                }
            }
            u16x8 af[4];
            #pragma unroll
            for (int ii = 0; ii < 4; ++ii) {
                int ra = wm + (ih * 4 + ii) * 16 + lr;
                af[ii] = *(const u16x8*)&Ab[ra * 64 + (((ks * 4 + half) ^ (ra & 7)) * 8)];
            }
            asm volatile("s_waitcnt lgkmcnt(0)" ::: "memory");
            __builtin_amdgcn_sched_barrier(0);
            __builtin_amdgcn_s_setprio(1);
            #pragma unroll
            for (int ii = 0; ii < 4; ++ii)
                #pragma unroll
                for (int j = 0; j < 4; ++j)
                    acc[ih * 4 + ii][j] = mfma_bf16(af[ii], bfr[j], acc[ih * 4 + ii][j]);
            __builtin_amdgcn_s_setprio(0);
        }

        if (t < 15) asm volatile("s_waitcnt vmcnt(0)" ::: "memory");
        __builtin_amdgcn_s_barrier();
    }

    // epilogue: scatter to Q(x0.125*log2e)/K/VT; V packed 4-wide (consecutive n)
    #pragma unroll
    for (int i = 0; i < 8; ++i) {
        int rowb = m0 + wm + i * 16 + half * 4;
        int b = rowb >> 11, n = rowb & 2047;
        int bh16 = (b << 4);
        #pragma unroll
        for (int j = 0; j < 4; ++j) {
            int col = n0 + wn + j * 16 + lr;
            int part = col >> 10, cj = col & 1023;
            int h = cj >> 6, d = cj & 63;
            int bh = bh16 + h;
            if (part == 0) {
                #pragma unroll
                for (int r = 0; r < 4; ++r)
                    Qs[((size_t)bh * 2048 + n + r) * 64 + d] = f2bf(acc[i][j][r] * 0.18033688f);
            } else if (part == 1) {
                #pragma unroll
                for (int r = 0; r < 4; ++r)
                    Ks[((size_t)bh * 2048 + n + r) * 64 + d] = f2bf(acc[i][j][r]);
            } else {
                u16x4 p;
                #pragma unroll
                for (int r = 0; r < 4; ++r) p[r] = f2bf(acc[i][j][r]);
                *(u16x4*)&VTs[((size_t)bh * 64 + d) * 2048 + n] = p;
            }
        }
    }
}

// ---------------- GEMM2 (out-proj): attn[8192][1024] @ woutT, +bias -> f32 ----
// R6-proven kernel (256x128, BK=64, 8 waves 4Mx2N, triple-buffer, 2-phase,
// counted vmcnt(6)); grid (8,32) = exactly one CU round; B (2MB) L2-resident.
__global__ __launch_bounds__(512, 1) void k_gemm2(
    const unsigned short* __restrict__ A,
    const unsigned short* __restrict__ BT,
    const float* __restrict__ bias,
    float* __restrict__ outf)
{
    __shared__ unsigned short As[3][256 * 64];
    __shared__ unsigned short Bs[3][128 * 64];
    const int K = 1024;
    const int tid = threadIdx.x, lane = tid & 63, wave = tid >> 6;

    int gx = gridDim.x;
    int nwg = gx * gridDim.y;
    int lin = blockIdx.y * gx + blockIdx.x;
    int virt = (lin & 7) * (nwg >> 3) + (lin >> 3);
    int bx = virt % gx, by = virt / gx;
    const int m0 = by * 256, n0 = bx * 128;

    const int wm = (wave >> 1) * 64, wn = (wave & 1) * 64;
    const int lr = lane & 15, half = lane >> 4;
    const int srow = lane >> 3, sslot = lane & 7;

    auto stage_sub = [&](int buf, int t, int h) {
        int k0 = t * 64;
        #pragma unroll
        for (int r = 0; r < 2; ++r) {
            int chunk = (h * 2 + r) * 8 + wave;
            int row = chunk * 8 + srow;
            int koff = (sslot ^ (row & 7)) * 8;
            gl_lds16(&A[(size_t)(m0 + row) * K + k0 + koff], &As[buf][chunk * 512]);
        }
        {
            int chunk = h * 8 + wave;
            int row = chunk * 8 + srow;
            int koff = (sslot ^ (row & 7)) * 8;
            gl_lds16(&BT[(size_t)(n0 + row) * K + k0 + koff], &Bs[buf][chunk * 512]);
        }
    };

    f32x4 acc[4][4] = {};

    stage_sub(0, 0, 0); stage_sub(0, 0, 1);
    stage_sub(1, 1, 0); stage_sub(1, 1, 1);
    asm volatile("s_waitcnt vmcnt(6)" ::: "memory");
    __builtin_amdgcn_s_barrier();

    for (int t = 0; t < 16; ++t) {
        const int cur = t % 3, nxt = (t + 2) % 3;
        const bool do_stage = (t + 2) < 16;
        const unsigned short* Ab = As[cur];
        const unsigned short* Bb = Bs[cur];

        #pragma unroll
        for (int ks = 0; ks < 2; ++ks) {
            u16x8 af[4], bfr[4];
            #pragma unroll
            for (int i = 0; i < 4; ++i) {
                int ra = wm + i * 16 + lr;
                af[i] = *(const u16x8*)&Ab[ra * 64 + (((ks * 4 + half) ^ (ra & 7)) * 8)];
                int rb = wn + i * 16 + lr;
                bfr[i] = *(const u16x8*)&Bb[rb * 64 + (((ks * 4 + half) ^ (rb & 7)) * 8)];
            }
            if (do_stage) stage_sub(nxt, t + 2, ks);
            if (ks == 1) {
                if (t < 14)       asm volatile("s_waitcnt vmcnt(6)" ::: "memory");
                else if (t == 14) asm volatile("s_waitcnt vmcnt(0)" ::: "memory");
            }
            __builtin_amdgcn_s_barrier();
            asm volatile("s_waitcnt lgkmcnt(0)" ::: "memory");
            __builtin_amdgcn_sched_barrier(0);
            __builtin_amdgcn_s_setprio(1);
            #pragma unroll
            for (int i = 0; i < 4; ++i)
                #pragma unroll
                for (int j = 0; j < 4; ++j)
                    acc[i][j] = mfma_bf16(af[i], bfr[j], acc[i][j]);
            __builtin_amdgcn_s_setprio(0);
            __builtin_amdgcn_s_barrier();
        }
    }

    #pragma unroll
    for (int i = 0; i < 4; ++i)
        #pragma unroll
        for (int j = 0; j < 4; ++j)
            #pragma unroll
            for (int r = 0; r < 4; ++r) {
                int row = m0 + wm + i * 16 + half * 4 + r;
                int col = n0 + wn + j * 16 + lr;
                outf[(size_t)row * 1024 + col] = acc[i][j][r] + bias[col];
            }
}

// ---------------- flash attention: swapped-QK 32x32, 2 q-blocks/wave --------
__global__ __launch_bounds__(256, 2) void k_attn(
    const unsigned short* __restrict__ Qs,
    const unsigned short* __restrict__ Ks,
    const unsigned short* __restrict__ VTs,
    unsigned short* __restrict__ attn)   // [8192][1024] bf16
{
    __shared__ unsigned short Kt[2][64 * 64];
    __shared__ unsigned short Vt[2][64 * 64];
    const int tid = threadIdx.x, lane = tid & 63, wave = tid >> 6;

    int lin = blockIdx.y * 8 + blockIdx.x;          // 512 wgs, bijective
    int virt = (lin & 7) * 64 + (lin >> 3);
    int bh = virt >> 3;
    int q0 = (virt & 7) * 256 + wave * 64;

    const int lq = lane & 31;
    const int hi = lane >> 5;
    const bool hib = hi != 0;

    const unsigned short* Kbase = Ks + (size_t)bh * 2048 * 64;
    const unsigned short* Vbase = VTs + (size_t)bh * 64 * 2048;

    u16x8 qf0[4], qf1[4];
    {
        const unsigned short* Qr0 = Qs + ((size_t)bh * 2048 + q0 + lq) * 64;
        const unsigned short* Qr1 = Qr0 + 32 * 64;
        #pragma unroll
        for (int kk = 0; kk < 4; ++kk) {
            qf0[kk] = *(const u16x8*)&Qr0[kk * 16 + hi * 8];
            qf1[kk] = *(const u16x8*)&Qr1[kk * 16 + hi * 8];
        }
    }

    const int srow_in = lane >> 4, sslot = lane & 15;
    auto stage = [&](int buf, int j0) {
        #pragma unroll
        for (int c = 0; c < 2; ++c) {
            int chunk = wave * 2 + c;
            int row = chunk * 4 + srow_in;           // 0..31
            int v = sslot ^ (row & 15);
            int high = v >> 3, dsl = (v & 7) * 8;
            gl_lds16(Kbase + (size_t)(j0 + high * 32 + row) * 64 + dsl, &Kt[buf][chunk * 512]);
            gl_lds16(Vbase + (size_t)(high * 32 + row) * 2048 + j0 + dsl, &Vt[buf][chunk * 512]);
        }
    };

    f32x16 o0[2] = {}, o1[2] = {};
    f32x16 osum0 = {}, osum1 = {};
    const u16x8 onesf = {0x3F80, 0x3F80, 0x3F80, 0x3F80, 0x3F80, 0x3F80, 0x3F80, 0x3F80};

    stage(0, 0);
    __syncthreads();
    int cur = 0;

    for (int t = 0; t < 32; ++t) {
        if (t < 31) stage(cur ^ 1, (t + 1) * 64);

        f32x16 sacc0[2] = {}, sacc1[2] = {};
        __builtin_amdgcn_s_setprio(1);
        #pragma unroll
        for (int jb = 0; jb < 2; ++jb) {
            u16x8 kf[4];
            #pragma unroll
            for (int kk = 0; kk < 4; ++kk) {
                int s = (jb * 8 + kk * 2 + hi) ^ (lq & 15);
                kf[kk] = *(const u16x8*)&Kt[cur][lq * 128 + s * 8];
            }
            #pragma unroll
            for (int kk = 0; kk < 4; ++kk) sacc0[jb] = mfma32(kf[kk], qf0[kk], sacc0[jb]);
            #pragma unroll
            for (int kk = 0; kk < 4; ++kk) sacc1[jb] = mfma32(kf[kk], qf1[kk], sacc1[jb]);
        }
        __builtin_amdgcn_s_setprio(0);

        unsigned int pk0[16], pk1[16];
        #pragma unroll
        for (int jb = 0; jb < 2; ++jb)
            #pragma unroll
            for (int i = 0; i < 8; ++i) {
                pk0[jb * 8 + i] = cvt_pk_bf16(fexp2(sacc0[jb][2 * i]), fexp2(sacc0[jb][2 * i + 1]));
                pk1[jb * 8 + i] = cvt_pk_bf16(fexp2(sacc1[jb][2 * i]), fexp2(sacc1[jb][2 * i + 1]));
            }

        #pragma unroll
        for (int kk = 0; kk < 4; ++kk) {
            const int base = (kk >> 1) * 8 + (kk & 1) * 4;
            unsigned int a0 = pk0[base + 0], a1 = pk0[base + 1], a2 = pk0[base + 2], a3 = pk0[base + 3];
            unsigned int b0 = pk1[base + 0], b1 = pk1[base + 1], b2 = pk1[base + 2], b3 = pk1[base + 3];
            unsigned int sa0 = __shfl_xor(a0, 32), sa1 = __shfl_xor(a1, 32);
            unsigned int sa2 = __shfl_xor(a2, 32), sa3 = __shfl_xor(a3, 32);
            unsigned int sb0 = __shfl_xor(b0, 32), sb1 = __shfl_xor(b1, 32);
            unsigned int sb2 = __shfl_xor(b2, 32), sb3 = __shfl_xor(b3, 32);
            u32x4 w0, w1;
            w0[0] = hib ? sa2 : a0;  w0[1] = hib ? sa3 : a1;
            w0[2] = hib ? a2 : sa0;  w0[3] = hib ? a3 : sa1;
            w1[0] = hib ? sb2 : b0;  w1[1] = hib ? sb3 : b1;
            w1[2] = hib ? b2 : sb0;  w1[3] = hib ? b3 : sb1;
            u16x8 pa0 = __builtin_bit_cast(u16x8, w0);
            u16x8 pa1 = __builtin_bit_cast(u16x8, w1);
            __builtin_amdgcn_s_setprio(1);
            osum0 = mfma32(pa0, onesf, osum0);
            osum1 = mfma32(pa1, onesf, osum1);
            #pragma unroll
            for (int db = 0; db < 2; ++db) {
                int s = (db * 8 + kk * 2 + hi) ^ (lq & 15);
                u16x8 vf = *(const u16x8*)&Vt[cur][lq * 128 + s * 8];
                o0[db] = mfma32(pa0, vf, o0[db]);
                o1[db] = mfma32(pa1, vf, o1[db]);
            }
            __builtin_amdgcn_s_setprio(0);
        }

        __syncthreads();
        cur ^= 1;
    }

    int b = bh >> 4, h = bh & 15;
    #pragma unroll
    for (int r = 0; r < 16; ++r) {
        int qrow = (r & 3) + 8 * (r >> 2) + 4 * hi;
        float i0 = frcp(osum0[r]);
        float i1 = frcp(osum1[r]);
        size_t ro0 = (size_t)(b * 2048 + q0 + qrow) * 1024 + h * 64;
        size_t ro1 = (size_t)(b * 2048 + q0 + 32 + qrow) * 1024 + h * 64;
        attn[ro0 + lq]      = f2bf(o0[0][r] * i0);
        attn[ro0 + 32 + lq] = f2bf(o0[1][r] * i0);
        attn[ro1 + lq]      = f2bf(o1[0][r] * i1);
        attn[ro1 + 32 + lq] = f2bf(o1[1][r] * i1);
    }
}

extern "C" void kernel_launch(void* const* d_in, const int* in_sizes, int n_in,
                              void* d_out, int out_size, void* d_ws, size_t ws_size,
                              hipStream_t stream) {
    const float* x     = (const float*)d_in[0];
    const float* w_qkv = (const float*)d_in[1];
    const float* w_out = (const float*)d_in[2];
    const float* b_out = (const float*)d_in[3];
    float* out = (float*)d_out;

    char* ws = (char*)d_ws;
    size_t off = 0;
    auto alloc = [&](size_t bytes) -> void* {
        void* p = ws + off;
        off += (bytes + 255) & ~(size_t)255;
        return p;
    };
    unsigned short* xb    = (unsigned short*)alloc(8192ull * 1024 * 2);
    unsigned short* wqkvT = (unsigned short*)alloc(3072ull * 1024 * 2);
    unsigned short* woutT = (unsigned short*)alloc(1024ull * 1024 * 2);
    unsigned short* Qs    = (unsigned short*)alloc(64ull * 2048 * 64 * 2);
    unsigned short* Ks    = (unsigned short*)alloc(64ull * 2048 * 64 * 2);
    unsigned short* VTs   = (unsigned short*)alloc(64ull * 2048 * 64 * 2);
    unsigned short* attn  = (unsigned short*)alloc(8192ull * 1024 * 2);
    if (off > ws_size) return;

    k_cvt<<<2048, 256, 0, stream>>>(x, xb, 8192 * 1024 / 4);
    k_transpose<<<dim3(3072 / 32, 1024 / 32), dim3(32, 8), 0, stream>>>(w_qkv, wqkvT, 1024, 3072);
    k_transpose<<<dim3(1024 / 32, 1024 / 32), dim3(32, 8), 0, stream>>>(w_out, woutT, 1024, 1024);
    k_gemm1<<<dim3(12, 32), 512, 0, stream>>>(xb, wqkvT, Qs, Ks, VTs);
    k_attn<<<dim3(8, 64), 256, 0, stream>>>(Qs, Ks, VTs, attn);
    k_gemm2<<<dim3(8, 32), 512, 0, stream>>>(attn, woutT, b_out, out);
}

// Round 9
// 208.410 us; speedup vs baseline: 1.1977x; 1.0040x over previous
//
#include <hip/hip_runtime.h>
#include <hip/hip_bf16.h>

// Problem: x[4,2048,1024] f32; w_qkv[1024,3072]; w_out[1024,1024]; b_out[1024]
// out[4,2048,1024] f32.  HEADS=16, DH=64, scale=0.125 (folded with log2e into Q).

typedef __attribute__((ext_vector_type(4))) float f32x4;
typedef __attribute__((ext_vector_type(16))) float f32x16;
typedef __attribute__((ext_vector_type(8))) unsigned short u16x8;
typedef __attribute__((ext_vector_type(4))) unsigned short u16x4;
typedef __attribute__((ext_vector_type(4))) unsigned int u32x4;
typedef __attribute__((ext_vector_type(8))) __bf16 bf16x8;

static __device__ __forceinline__ f32x4 mfma_bf16(u16x8 a, u16x8 b, f32x4 c) {
    return __builtin_amdgcn_mfma_f32_16x16x32_bf16(
        __builtin_bit_cast(bf16x8, a), __builtin_bit_cast(bf16x8, b), c, 0, 0, 0);
}
static __device__ __forceinline__ f32x16 mfma32(u16x8 a, u16x8 b, f32x16 c) {
    return __builtin_amdgcn_mfma_f32_32x32x16_bf16(
        __builtin_bit_cast(bf16x8, a), __builtin_bit_cast(bf16x8, b), c, 0, 0, 0);
}

static __device__ __forceinline__ unsigned short f2bf(float f) {
    unsigned int u = __builtin_bit_cast(unsigned int, f);
    u += 0x7fffu + ((u >> 16) & 1u);   // RNE
    return (unsigned short)(u >> 16);
}
static __device__ __forceinline__ unsigned int cvt_pk_bf16(float a, float b) {
    unsigned int r;
    asm("v_cvt_pk_bf16_f32 %0, %1, %2" : "=v"(r) : "v"(a), "v"(b));
    return r;
}
static __device__ __forceinline__ float fexp2(float x) {   // D = 2^S0
    float r;
    asm("v_exp_f32 %0, %1" : "=v"(r) : "v"(x));
    return r;
}
static __device__ __forceinline__ float frcp(float x) {
    float r;
    asm("v_rcp_f32 %0, %1" : "=v"(r) : "v"(x));
    return r;
}
typedef const __attribute__((address_space(1))) unsigned int* gp1_t;
typedef __attribute__((address_space(3))) unsigned int* lp3_t;
static __device__ __forceinline__ void gl_lds16(const void* g, void* l) {
    __builtin_amdgcn_global_load_lds((gp1_t)g, (lp3_t)l, 16, 0, 0);
}

// ---------------- convert x (f32 -> bf16), vectorized ----------------
__global__ void k_cvt(const float* __restrict__ in, unsigned short* __restrict__ out, int n4) {
    int i = blockIdx.x * blockDim.x + threadIdx.x;
    int stride = gridDim.x * blockDim.x;
    for (; i < n4; i += stride) {
        f32x4 v = ((const f32x4*)in)[i];
        u16x4 o;
        #pragma unroll
        for (int j = 0; j < 4; ++j) o[j] = f2bf(v[j]);
        ((u16x4*)out)[i] = o;
    }
}

// ---------------- transpose f32 [R][C] -> bf16 [C][R] ----------------
__global__ void k_transpose(const float* __restrict__ in, unsigned short* __restrict__ out,
                            int R, int C) {
    __shared__ float tile[32][33];
    int c0 = blockIdx.x * 32, r0 = blockIdx.y * 32;
    int tx = threadIdx.x, ty = threadIdx.y;   // block (32,8)
    #pragma unroll
    for (int i = ty; i < 32; i += 8)
        tile[i][tx] = in[(size_t)(r0 + i) * C + c0 + tx];
    __syncthreads();
    #pragma unroll
    for (int i = ty; i < 32; i += 8)
        out[(size_t)(c0 + i) * R + r0 + tx] = f2bf(tile[tx][i]);
}

// ---------------- GEMM1 (QKV): A[8192][1024] @ BT[3072][1024] ----------------
// 128x128 tile, BK=32, 4 waves 2Mx2N (wave 64x64), double-buffered 32KB LDS ->
// 4 blocks/CU (16 waves/CU): stall-hiding by deep co-residency (m97 regime).
// grid (24,64)=1536 = exact 6 rounds of 256. Column XCD map: 3 B-panels/XCD
// (768KB, L2-resident).
__global__ __launch_bounds__(256, 4) void k_gemm1(
    const unsigned short* __restrict__ A,
    const unsigned short* __restrict__ BT,
    unsigned short* __restrict__ Qs,
    unsigned short* __restrict__ Ks,
    unsigned short* __restrict__ VTs)
{
    __shared__ unsigned short As[2][128 * 32];
    __shared__ unsigned short Bs[2][128 * 32];
    const int K = 1024;
    const int tid = threadIdx.x, lane = tid & 63, wave = tid >> 6;

    int lin = blockIdx.y * 24 + blockIdx.x;    // 0..1535
    int xcd = lin & 7, idx = lin >> 3;         // idx 0..191
    int virt = xcd * 192 + idx;
    int bx = virt >> 6, by = virt & 63;        // 3 bx-panels per XCD
    const int m0 = by * 128, n0 = bx * 128;

    const int wm = (wave >> 1) * 64, wn = (wave & 1) * 64;
    const int lr = lane & 15, half = lane >> 4;

    // staging: chunk = 1KB = 16 rows x 4 slots(16B). LDS[row][s] holds global
    // k-chunk s ^ ((row>>1)&3)  (2-way banks on read, verified R4).
    const int srow_in = lane >> 2, sslot = lane & 3;
    auto stage = [&](int buf, int t) {
        int k0 = t * 32;
        #pragma unroll
        for (int c = 0; c < 2; ++c) {
            int chunk = wave * 2 + c;
            int row = chunk * 16 + srow_in;
            int gk = (sslot ^ ((row >> 1) & 3)) * 8;
            gl_lds16(&A[(size_t)(m0 + row) * K + k0 + gk], &As[buf][chunk * 512]);
            gl_lds16(&BT[(size_t)(n0 + row) * K + k0 + gk], &Bs[buf][chunk * 512]);
        }
    };

    f32x4 acc[4][4] = {};

    stage(0, 0);
    __syncthreads();

    for (int t = 0; t < 32; ++t) {
        const int cur = t & 1;
        if (t < 31) stage(cur ^ 1, t + 1);
        const unsigned short* Ab = As[cur];
        const unsigned short* Bb = Bs[cur];

        u16x8 af[4], bfr[4];
        #pragma unroll
        for (int i = 0; i < 4; ++i) {
            int ra = wm + i * 16 + lr;
            af[i] = *(const u16x8*)&Ab[ra * 32 + ((half ^ ((ra >> 1) & 3)) * 8)];
            int rb = wn + i * 16 + lr;
            bfr[i] = *(const u16x8*)&Bb[rb * 32 + ((half ^ ((rb >> 1) & 3)) * 8)];
        }
        __builtin_amdgcn_s_setprio(1);
        #pragma unroll
        for (int i = 0; i < 4; ++i)
            #pragma unroll
            for (int j = 0; j < 4; ++j)
                acc[i][j] = mfma_bf16(af[i], bfr[j], acc[i][j]);
        __builtin_amdgcn_s_setprio(0);

        __syncthreads();   // drains vmcnt (stage) + lgkm; buffers flip
    }

    // epilogue: scatter Q(xscale)/K/VT; V packed 4-wide over consecutive n
    #pragma unroll
    for (int i = 0; i < 4; ++i) {
        int rowb = m0 + wm + i * 16 + half * 4;
        int b = rowb >> 11, n = rowb & 2047;
        int bh16 = (b << 4);
        #pragma unroll
        for (int j = 0; j < 4; ++j) {
            int col = n0 + wn + j * 16 + lr;
            int part = col >> 10, cj = col & 1023;
            int h = cj >> 6, d = cj & 63;
            int bh = bh16 + h;
            if (part == 0) {
                #pragma unroll
                for (int r = 0; r < 4; ++r)
                    Qs[((size_t)bh * 2048 + n + r) * 64 + d] = f2bf(acc[i][j][r] * 0.18033688f);
            } else if (part == 1) {
                #pragma unroll
                for (int r = 0; r < 4; ++r)
                    Ks[((size_t)bh * 2048 + n + r) * 64 + d] = f2bf(acc[i][j][r]);
            } else {
                u16x4 p;
                #pragma unroll
                for (int r = 0; r < 4; ++r) p[r] = f2bf(acc[i][j][r]);
                *(u16x4*)&VTs[((size_t)bh * 64 + d) * 2048 + n] = p;
            }
        }
    }
}

// ---------------- GEMM2 (out-proj): attn[8192][1024] @ woutT, +bias -> f32 ----
__global__ __launch_bounds__(512, 1) void k_gemm2(
    const unsigned short* __restrict__ A,
    const unsigned short* __restrict__ BT,
    const float* __restrict__ bias,
    float* __restrict__ outf)
{
    __shared__ unsigned short As[3][256 * 64];
    __shared__ unsigned short Bs[3][128 * 64];
    const int K = 1024;
    const int tid = threadIdx.x, lane = tid & 63, wave = tid >> 6;

    int gx = gridDim.x;
    int nwg = gx * gridDim.y;
    int lin = blockIdx.y * gx + blockIdx.x;
    int virt = (lin & 7) * (nwg >> 3) + (lin >> 3);
    int bx = virt % gx, by = virt / gx;
    const int m0 = by * 256, n0 = bx * 128;

    const int wm = (wave >> 1) * 64, wn = (wave & 1) * 64;
    const int lr = lane & 15, half = lane >> 4;
    const int srow = lane >> 3, sslot = lane & 7;

    auto stage_sub = [&](int buf, int t, int h) {
        int k0 = t * 64;
        #pragma unroll
        for (int r = 0; r < 2; ++r) {
            int chunk = (h * 2 + r) * 8 + wave;
            int row = chunk * 8 + srow;
            int koff = (sslot ^ (row & 7)) * 8;
            gl_lds16(&A[(size_t)(m0 + row) * K + k0 + koff], &As[buf][chunk * 512]);
        }
        {
            int chunk = h * 8 + wave;
            int row = chunk * 8 + srow;
            int koff = (sslot ^ (row & 7)) * 8;
            gl_lds16(&BT[(size_t)(n0 + row) * K + k0 + koff], &Bs[buf][chunk * 512]);
        }
    };

    f32x4 acc[4][4] = {};

    stage_sub(0, 0, 0); stage_sub(0, 0, 1);
    stage_sub(1, 1, 0); stage_sub(1, 1, 1);
    asm volatile("s_waitcnt vmcnt(6)" ::: "memory");
    __builtin_amdgcn_s_barrier();

    for (int t = 0; t < 16; ++t) {
        const int cur = t % 3, nxt = (t + 2) % 3;
        const bool do_stage = (t + 2) < 16;
        const unsigned short* Ab = As[cur];
        const unsigned short* Bb = Bs[cur];

        #pragma unroll
        for (int ks = 0; ks < 2; ++ks) {
            u16x8 af[4], bfr[4];
            #pragma unroll
            for (int i = 0; i < 4; ++i) {
                int ra = wm + i * 16 + lr;
                af[i] = *(const u16x8*)&Ab[ra * 64 + (((ks * 4 + half) ^ (ra & 7)) * 8)];
                int rb = wn + i * 16 + lr;
                bfr[i] = *(const u16x8*)&Bb[rb * 64 + (((ks * 4 + half) ^ (rb & 7)) * 8)];
            }
            if (do_stage) stage_sub(nxt, t + 2, ks);
            if (ks == 1) {
                if (t < 14)       asm volatile("s_waitcnt vmcnt(6)" ::: "memory");
                else if (t == 14) asm volatile("s_waitcnt vmcnt(0)" ::: "memory");
            }
            __builtin_amdgcn_s_barrier();
            asm volatile("s_waitcnt lgkmcnt(0)" ::: "memory");
            __builtin_amdgcn_sched_barrier(0);
            __builtin_amdgcn_s_setprio(1);
            #pragma unroll
            for (int i = 0; i < 4; ++i)
                #pragma unroll
                for (int j = 0; j < 4; ++j)
                    acc[i][j] = mfma_bf16(af[i], bfr[j], acc[i][j]);
            __builtin_amdgcn_s_setprio(0);
            __builtin_amdgcn_s_barrier();
        }
    }

    #pragma unroll
    for (int i = 0; i < 4; ++i)
        #pragma unroll
        for (int j = 0; j < 4; ++j)
            #pragma unroll
            for (int r = 0; r < 4; ++r) {
                int row = m0 + wm + i * 16 + half * 4 + r;
                int col = n0 + wn + j * 16 + lr;
                outf[(size_t)row * 1024 + col] = acc[i][j][r] + bias[col];
            }
}

// ---------------- flash attention: swapped-QK 32x32, 1 q-block/wave ---------
// grid (16,64) = 1024 blocks -> 4 blocks/CU (16 waves/CU) for stall hiding.
// LDS tiles: 32 rows x 256B, 16-slot XOR swizzle (2-way max = free).
// p = 2^s directly (scale*log2e folded into Q); row sums via ones-MFMA.
__global__ __launch_bounds__(256, 4) void k_attn(
    const unsigned short* __restrict__ Qs,
    const unsigned short* __restrict__ Ks,
    const unsigned short* __restrict__ VTs,
    unsigned short* __restrict__ attn)   // [8192][1024] bf16
{
    __shared__ unsigned short Kt[2][64 * 64];
    __shared__ unsigned short Vt[2][64 * 64];
    const int tid = threadIdx.x, lane = tid & 63, wave = tid >> 6;

    int lin = blockIdx.y * 16 + blockIdx.x;   // 1024 wgs, bijective XCD map
    int virt = (lin & 7) * 128 + (lin >> 3);
    int bh = virt >> 4;                       // 8 bh per XCD (4MB K/V in L2)
    int q0 = (virt & 15) * 128 + wave * 32;

    const int lq = lane & 31;
    const int hi = lane >> 5;
    const bool hib = hi != 0;

    const unsigned short* Kbase = Ks + (size_t)bh * 2048 * 64;
    const unsigned short* Vbase = VTs + (size_t)bh * 64 * 2048;

    u16x8 qf[4];
    {
        const unsigned short* Qr = Qs + ((size_t)bh * 2048 + q0 + lq) * 64;
        #pragma unroll
        for (int kk = 0; kk < 4; ++kk)
            qf[kk] = *(const u16x8*)&Qr[kk * 16 + hi * 8];
    }

    const int srow_in = lane >> 4, sslot = lane & 15;
    auto stage = [&](int buf, int j0) {
        #pragma unroll
        for (int c = 0; c < 2; ++c) {
            int chunk = wave * 2 + c;
            int row = chunk * 4 + srow_in;           // 0..31
            int v = sslot ^ (row & 15);
            int high = v >> 3, dsl = (v & 7) * 8;
            gl_lds16(Kbase + (size_t)(j0 + high * 32 + row) * 64 + dsl, &Kt[buf][chunk * 512]);
            gl_lds16(Vbase + (size_t)(high * 32 + row) * 2048 + j0 + dsl, &Vt[buf][chunk * 512]);
        }
    };

    f32x16 o[2] = {};
    f32x16 osum = {};
    const u16x8 onesf = {0x3F80, 0x3F80, 0x3F80, 0x3F80, 0x3F80, 0x3F80, 0x3F80, 0x3F80};

    stage(0, 0);
    __syncthreads();
    int cur = 0;

    for (int t = 0; t < 32; ++t) {
        if (t < 31) stage(cur ^ 1, (t + 1) * 64);

        // ---- QK^T: S^T[j][q] in log2 units ----
        f32x16 sacc[2] = {};
        __builtin_amdgcn_s_setprio(1);
        #pragma unroll
        for (int jb = 0; jb < 2; ++jb) {
            u16x8 kf[4];
            #pragma unroll
            for (int kk = 0; kk < 4; ++kk) {
                int s = (jb * 8 + kk * 2 + hi) ^ (lq & 15);
                kf[kk] = *(const u16x8*)&Kt[cur][lq * 128 + s * 8];
            }
            #pragma unroll
            for (int kk = 0; kk < 4; ++kk)
                sacc[jb] = mfma32(kf[kk], qf[kk], sacc[jb]);
        }
        __builtin_amdgcn_s_setprio(0);

        // ---- p = 2^s, pack to bf16 pairs ----
        unsigned int pk[16];
        #pragma unroll
        for (int jb = 0; jb < 2; ++jb)
            #pragma unroll
            for (int i = 0; i < 8; ++i)
                pk[jb * 8 + i] = cvt_pk_bf16(fexp2(sacc[jb][2 * i]), fexp2(sacc[jb][2 * i + 1]));

        // ---- PV + ones-MFMA row sums ----
        #pragma unroll
        for (int kk = 0; kk < 4; ++kk) {
            const int base = (kk >> 1) * 8 + (kk & 1) * 4;
            unsigned int a0 = pk[base + 0], a1 = pk[base + 1], a2 = pk[base + 2], a3 = pk[base + 3];
            unsigned int sa0 = __shfl_xor(a0, 32), sa1 = __shfl_xor(a1, 32);
            unsigned int sa2 = __shfl_xor(a2, 32), sa3 = __shfl_xor(a3, 32);
            u32x4 w0;
            w0[0] = hib ? sa2 : a0;  w0[1] = hib ? sa3 : a1;
            w0[2] = hib ? a2 : sa0;  w0[3] = hib ? a3 : sa1;
            u16x8 pa = __builtin_bit_cast(u16x8, w0);
            __builtin_amdgcn_s_setprio(1);
            osum = mfma32(pa, onesf, osum);
            #pragma unroll
            for (int db = 0; db < 2; ++db) {
                int s = (db * 8 + kk * 2 + hi) ^ (lq & 15);
                u16x8 vf = *(const u16x8*)&Vt[cur][lq * 128 + s * 8];
                o[db] = mfma32(pa, vf, o[db]);
            }
            __builtin_amdgcn_s_setprio(0);
        }

        __syncthreads();
        cur ^= 1;
    }

    // ---- epilogue: normalize and store (osum rows match o rows) ----
    int b = bh >> 4, h = bh & 15;
    #pragma unroll
    for (int r = 0; r < 16; ++r) {
        int qrow = (r & 3) + 8 * (r >> 2) + 4 * hi;
        float invr = frcp(osum[r]);
        size_t ro = (size_t)(b * 2048 + q0 + qrow) * 1024 + h * 64;
        attn[ro + lq]      = f2bf(o[0][r] * invr);
        attn[ro + 32 + lq] = f2bf(o[1][r] * invr);
    }
}

extern "C" void kernel_launch(void* const* d_in, const int* in_sizes, int n_in,
                              void* d_out, int out_size, void* d_ws, size_t ws_size,
                              hipStream_t stream) {
    const float* x     = (const float*)d_in[0];
    const float* w_qkv = (const float*)d_in[1];
    const float* w_out = (const float*)d_in[2];
    const float* b_out = (const float*)d_in[3];
    float* out = (float*)d_out;

    char* ws = (char*)d_ws;
    size_t off = 0;
    auto alloc = [&](size_t bytes) -> void* {
        void* p = ws + off;
        off += (bytes + 255) & ~(size_t)255;
        return p;
    };
    unsigned short* xb    = (unsigned short*)alloc(8192ull * 1024 * 2);
    unsigned short* wqkvT = (unsigned short*)alloc(3072ull * 1024 * 2);
    unsigned short* woutT = (unsigned short*)alloc(1024ull * 1024 * 2);
    unsigned short* Qs    = (unsigned short*)alloc(64ull * 2048 * 64 * 2);
    unsigned short* Ks    = (unsigned short*)alloc(64ull * 2048 * 64 * 2);
    unsigned short* VTs   = (unsigned short*)alloc(64ull * 2048 * 64 * 2);
    unsigned short* attn  = (unsigned short*)alloc(8192ull * 1024 * 2);
    if (off > ws_size) return;

    k_cvt<<<2048, 256, 0, stream>>>(x, xb, 8192 * 1024 / 4);
    k_transpose<<<dim3(3072 / 32, 1024 / 32), dim3(32, 8), 0, stream>>>(w_qkv, wqkvT, 1024, 3072);
    k_transpose<<<dim3(1024 / 32, 1024 / 32), dim3(32, 8), 0, stream>>>(w_out, woutT, 1024, 1024);
    k_gemm1<<<dim3(24, 64), 256, 0, stream>>>(xb, wqkvT, Qs, Ks, VTs);
    k_attn<<<dim3(16, 64), 256, 0, stream>>>(Qs, Ks, VTs, attn);
    k_gemm2<<<dim3(8, 32), 512, 0, stream>>>(attn, woutT, b_out, out);
}

// Round 10
// 203.648 us; speedup vs baseline: 1.2257x; 1.0234x over previous
//
#include <hip/hip_runtime.h>
#include <hip/hip_bf16.h>

// Problem: x[4,2048,1024] f32; w_qkv[1024,3072]; w_out[1024,1024]; b_out[1024]
// out[4,2048,1024] f32.  HEADS=16, DH=64, scale=0.125 (x log2e folded into wqkvT).

typedef __attribute__((ext_vector_type(4))) float f32x4;
typedef __attribute__((ext_vector_type(16))) float f32x16;
typedef __attribute__((ext_vector_type(8))) unsigned short u16x8;
typedef __attribute__((ext_vector_type(4))) unsigned short u16x4;
typedef __attribute__((ext_vector_type(4))) unsigned int u32x4;
typedef __attribute__((ext_vector_type(8))) __bf16 bf16x8;

static __device__ __forceinline__ f32x4 mfma_bf16(u16x8 a, u16x8 b, f32x4 c) {
    return __builtin_amdgcn_mfma_f32_16x16x32_bf16(
        __builtin_bit_cast(bf16x8, a), __builtin_bit_cast(bf16x8, b), c, 0, 0, 0);
}
static __device__ __forceinline__ f32x16 mfma32(u16x8 a, u16x8 b, f32x16 c) {
    return __builtin_amdgcn_mfma_f32_32x32x16_bf16(
        __builtin_bit_cast(bf16x8, a), __builtin_bit_cast(bf16x8, b), c, 0, 0, 0);
}

static __device__ __forceinline__ unsigned short f2bf(float f) {
    unsigned int u = __builtin_bit_cast(unsigned int, f);
    u += 0x7fffu + ((u >> 16) & 1u);   // RNE
    return (unsigned short)(u >> 16);
}
static __device__ __forceinline__ unsigned int cvt_pk_bf16(float a, float b) {
    unsigned int r;
    asm("v_cvt_pk_bf16_f32 %0, %1, %2" : "=v"(r) : "v"(a), "v"(b));
    return r;
}
static __device__ __forceinline__ float fexp2(float x) {   // D = 2^S0
    float r;
    asm("v_exp_f32 %0, %1" : "=v"(r) : "v"(x));
    return r;
}
static __device__ __forceinline__ float frcp(float x) {
    float r;
    asm("v_rcp_f32 %0, %1" : "=v"(r) : "v"(x));
    return r;
}
typedef const __attribute__((address_space(1))) unsigned int* gp1_t;
typedef __attribute__((address_space(3))) unsigned int* lp3_t;
static __device__ __forceinline__ void gl_lds16(const void* g, void* l) {
    __builtin_amdgcn_global_load_lds((gp1_t)g, (lp3_t)l, 16, 0, 0);
}

// ---------------- convert x (f32 -> bf16), vectorized ----------------
__global__ void k_cvt(const float* __restrict__ in, unsigned short* __restrict__ out, int n4) {
    int i = blockIdx.x * blockDim.x + threadIdx.x;
    int stride = gridDim.x * blockDim.x;
    for (; i < n4; i += stride) {
        f32x4 v = ((const f32x4*)in)[i];
        u16x4 o;
        #pragma unroll
        for (int j = 0; j < 4; ++j) o[j] = f2bf(v[j]);
        ((u16x4*)out)[i] = o;
    }
}

// ---- transpose f32 [R][C] -> bf16 [C][R]; rows < scale_rows get *scale ----
__global__ void k_transpose_sc(const float* __restrict__ in, unsigned short* __restrict__ out,
                               int R, int C, int scale_rows, float scale) {
    __shared__ float tile[32][33];
    int c0 = blockIdx.x * 32, r0 = blockIdx.y * 32;
    int tx = threadIdx.x, ty = threadIdx.y;   // block (32,8)
    #pragma unroll
    for (int i = ty; i < 32; i += 8)
        tile[i][tx] = in[(size_t)(r0 + i) * C + c0 + tx];
    __syncthreads();
    #pragma unroll
    for (int i = ty; i < 32; i += 8) {
        float v = tile[tx][i];
        if (c0 + i < scale_rows) v *= scale;
        out[(size_t)(c0 + i) * R + r0 + tx] = f2bf(v);
    }
}

// ---------------- GEMM1 (QKV): xb[8192][1024] @ wqkvT[3072][1024] -> qkv bf16 ----
// Verbatim gemm2 structure: 256x128, BK=64, 8 waves 4Mx2N, triple-buffer,
// counted vmcnt(6). Clean coalesced bf16 stores (no scatter). A-panel-resident
// XCD map: 4 M-panels (2MB) per XCD in L2; B streamed (L3-served).
__global__ __launch_bounds__(512, 1) void k_gemm1(
    const unsigned short* __restrict__ A,
    const unsigned short* __restrict__ BT,
    unsigned short* __restrict__ qkv)
{
    __shared__ unsigned short As[3][256 * 64];
    __shared__ unsigned short Bs[3][128 * 64];
    const int K = 1024;
    const int tid = threadIdx.x, lane = tid & 63, wave = tid >> 6;

    // grid (24,32) = 768 blocks; per XCD 96: by = virt/24 (4 panels), bx fast
    int lin = blockIdx.y * 24 + blockIdx.x;
    int xcd = lin & 7, idx = lin >> 3;
    int virt = xcd * 96 + idx;
    int by = virt / 24, bx = virt % 24;
    const int m0 = by * 256, n0 = bx * 128;

    const int wm = (wave >> 1) * 64, wn = (wave & 1) * 64;
    const int lr = lane & 15, half = lane >> 4;
    const int srow = lane >> 3, sslot = lane & 7;

    auto stage_sub = [&](int buf, int t, int h) {
        int k0 = t * 64;
        #pragma unroll
        for (int r = 0; r < 2; ++r) {
            int chunk = (h * 2 + r) * 8 + wave;
            int row = chunk * 8 + srow;
            int koff = (sslot ^ (row & 7)) * 8;
            gl_lds16(&A[(size_t)(m0 + row) * K + k0 + koff], &As[buf][chunk * 512]);
        }
        {
            int chunk = h * 8 + wave;
            int row = chunk * 8 + srow;
            int koff = (sslot ^ (row & 7)) * 8;
            gl_lds16(&BT[(size_t)(n0 + row) * K + k0 + koff], &Bs[buf][chunk * 512]);
        }
    };

    f32x4 acc[4][4] = {};

    stage_sub(0, 0, 0); stage_sub(0, 0, 1);
    stage_sub(1, 1, 0); stage_sub(1, 1, 1);
    asm volatile("s_waitcnt vmcnt(6)" ::: "memory");
    __builtin_amdgcn_s_barrier();

    for (int t = 0; t < 16; ++t) {
        const int cur = t % 3, nxt = (t + 2) % 3;
        const bool do_stage = (t + 2) < 16;
        const unsigned short* Ab = As[cur];
        const unsigned short* Bb = Bs[cur];

        #pragma unroll
        for (int ks = 0; ks < 2; ++ks) {
            u16x8 af[4], bfr[4];
            #pragma unroll
            for (int i = 0; i < 4; ++i) {
                int ra = wm + i * 16 + lr;
                af[i] = *(const u16x8*)&Ab[ra * 64 + (((ks * 4 + half) ^ (ra & 7)) * 8)];
                int rb = wn + i * 16 + lr;
                bfr[i] = *(const u16x8*)&Bb[rb * 64 + (((ks * 4 + half) ^ (rb & 7)) * 8)];
            }
            if (do_stage) stage_sub(nxt, t + 2, ks);
            if (ks == 1) {
                if (t < 14)       asm volatile("s_waitcnt vmcnt(6)" ::: "memory");
                else if (t == 14) asm volatile("s_waitcnt vmcnt(0)" ::: "memory");
            }
            __builtin_amdgcn_s_barrier();
            asm volatile("s_waitcnt lgkmcnt(0)" ::: "memory");
            __builtin_amdgcn_sched_barrier(0);
            __builtin_amdgcn_s_setprio(1);
            #pragma unroll
            for (int i = 0; i < 4; ++i)
                #pragma unroll
                for (int j = 0; j < 4; ++j)
                    acc[i][j] = mfma_bf16(af[i], bfr[j], acc[i][j]);
            __builtin_amdgcn_s_setprio(0);
            __builtin_amdgcn_s_barrier();
        }
    }

    #pragma unroll
    for (int i = 0; i < 4; ++i)
        #pragma unroll
        for (int j = 0; j < 4; ++j)
            #pragma unroll
            for (int r = 0; r < 4; ++r) {
                int row = m0 + wm + i * 16 + half * 4 + r;
                int col = n0 + wn + j * 16 + lr;
                qkv[(size_t)row * 3072 + col] = f2bf(acc[i][j][r]);
            }
}

// ---------------- V transpose: qkv V-part -> VTs[bh][64 d][2048 n] bf16 ------
__global__ void k_vtrans(const unsigned short* __restrict__ qkv,
                         unsigned short* __restrict__ VTs) {
    __shared__ unsigned short tile[32][33];
    int bh = blockIdx.y >> 1, dt = blockIdx.y & 1;
    int b = bh >> 4, h = bh & 15;
    int n0 = blockIdx.x * 32, d0 = dt * 32;
    int tx = threadIdx.x, ty = threadIdx.y;   // block (32,8)
    const unsigned short* src = qkv + (size_t)(b * 2048) * 3072 + 2048 + h * 64 + d0;
    #pragma unroll
    for (int i = ty; i < 32; i += 8)
        tile[i][tx] = src[(size_t)(n0 + i) * 3072 + tx];
    __syncthreads();
    #pragma unroll
    for (int i = ty; i < 32; i += 8)
        VTs[((size_t)bh * 64 + d0 + i) * 2048 + n0 + tx] = tile[tx][i];
}

// ---------------- GEMM2 (out-proj): attn[8192][1024] @ woutT, +bias -> f32 ----
__global__ __launch_bounds__(512, 1) void k_gemm2(
    const unsigned short* __restrict__ A,
    const unsigned short* __restrict__ BT,
    const float* __restrict__ bias,
    float* __restrict__ outf)
{
    __shared__ unsigned short As[3][256 * 64];
    __shared__ unsigned short Bs[3][128 * 64];
    const int K = 1024;
    const int tid = threadIdx.x, lane = tid & 63, wave = tid >> 6;

    int gx = gridDim.x;
    int nwg = gx * gridDim.y;
    int lin = blockIdx.y * gx + blockIdx.x;
    int virt = (lin & 7) * (nwg >> 3) + (lin >> 3);
    int bx = virt % gx, by = virt / gx;
    const int m0 = by * 256, n0 = bx * 128;

    const int wm = (wave >> 1) * 64, wn = (wave & 1) * 64;
    const int lr = lane & 15, half = lane >> 4;
    const int srow = lane >> 3, sslot = lane & 7;

    auto stage_sub = [&](int buf, int t, int h) {
        int k0 = t * 64;
        #pragma unroll
        for (int r = 0; r < 2; ++r) {
            int chunk = (h * 2 + r) * 8 + wave;
            int row = chunk * 8 + srow;
            int koff = (sslot ^ (row & 7)) * 8;
            gl_lds16(&A[(size_t)(m0 + row) * K + k0 + koff], &As[buf][chunk * 512]);
        }
        {
            int chunk = h * 8 + wave;
            int row = chunk * 8 + srow;
            int koff = (sslot ^ (row & 7)) * 8;
            gl_lds16(&BT[(size_t)(n0 + row) * K + k0 + koff], &Bs[buf][chunk * 512]);
        }
    };

    f32x4 acc[4][4] = {};

    stage_sub(0, 0, 0); stage_sub(0, 0, 1);
    stage_sub(1, 1, 0); stage_sub(1, 1, 1);
    asm volatile("s_waitcnt vmcnt(6)" ::: "memory");
    __builtin_amdgcn_s_barrier();

    for (int t = 0; t < 16; ++t) {
        const int cur = t % 3, nxt = (t + 2) % 3;
        const bool do_stage = (t + 2) < 16;
        const unsigned short* Ab = As[cur];
        const unsigned short* Bb = Bs[cur];

        #pragma unroll
        for (int ks = 0; ks < 2; ++ks) {
            u16x8 af[4], bfr[4];
            #pragma unroll
            for (int i = 0; i < 4; ++i) {
                int ra = wm + i * 16 + lr;
                af[i] = *(const u16x8*)&Ab[ra * 64 + (((ks * 4 + half) ^ (ra & 7)) * 8)];
                int rb = wn + i * 16 + lr;
                bfr[i] = *(const u16x8*)&Bb[rb * 64 + (((ks * 4 + half) ^ (rb & 7)) * 8)];
            }
            if (do_stage) stage_sub(nxt, t + 2, ks);
            if (ks == 1) {
                if (t < 14)       asm volatile("s_waitcnt vmcnt(6)" ::: "memory");
                else if (t == 14) asm volatile("s_waitcnt vmcnt(0)" ::: "memory");
            }
            __builtin_amdgcn_s_barrier();
            asm volatile("s_waitcnt lgkmcnt(0)" ::: "memory");
            __builtin_amdgcn_sched_barrier(0);
            __builtin_amdgcn_s_setprio(1);
            #pragma unroll
            for (int i = 0; i < 4; ++i)
                #pragma unroll
                for (int j = 0; j < 4; ++j)
                    acc[i][j] = mfma_bf16(af[i], bfr[j], acc[i][j]);
            __builtin_amdgcn_s_setprio(0);
            __builtin_amdgcn_s_barrier();
        }
    }

    #pragma unroll
    for (int i = 0; i < 4; ++i)
        #pragma unroll
        for (int j = 0; j < 4; ++j)
            #pragma unroll
            for (int r = 0; r < 4; ++r) {
                int row = m0 + wm + i * 16 + half * 4 + r;
                int col = n0 + wn + j * 16 + lr;
                outf[(size_t)row * 1024 + col] = acc[i][j][r] + bias[col];
            }
}

// ---------------- flash attention: swapped-QK 32x32, 1 q-block/wave ---------
// R9 structure unchanged; Q/K read directly from qkv[8192][3072] (Q pre-scaled
// via wqkvT), V from VTs. grid (16,64), 4 blocks/CU.
__global__ __launch_bounds__(256, 4) void k_attn(
    const unsigned short* __restrict__ qkv,
    const unsigned short* __restrict__ VTs,
    unsigned short* __restrict__ attn)   // [8192][1024] bf16
{
    __shared__ unsigned short Kt[2][64 * 64];
    __shared__ unsigned short Vt[2][64 * 64];
    const int tid = threadIdx.x, lane = tid & 63, wave = tid >> 6;

    int lin = blockIdx.y * 16 + blockIdx.x;   // 1024 wgs, bijective XCD map
    int virt = (lin & 7) * 128 + (lin >> 3);
    int bh = virt >> 4;
    int q0 = (virt & 15) * 128 + wave * 32;

    const int lq = lane & 31;
    const int hi = lane >> 5;
    const bool hib = hi != 0;

    int b = bh >> 4, h = bh & 15;
    const unsigned short* Kq = qkv + (size_t)(b * 2048) * 3072 + 1024 + h * 64;
    const unsigned short* Vbase = VTs + (size_t)bh * 64 * 2048;

    u16x8 qf[4];
    {
        const unsigned short* Qr = qkv + (size_t)(b * 2048 + q0 + lq) * 3072 + h * 64;
        #pragma unroll
        for (int kk = 0; kk < 4; ++kk)
            qf[kk] = *(const u16x8*)&Qr[kk * 16 + hi * 8];
    }

    const int srow_in = lane >> 4, sslot = lane & 15;
    auto stage = [&](int buf, int j0) {
        #pragma unroll
        for (int c = 0; c < 2; ++c) {
            int chunk = wave * 2 + c;
            int row = chunk * 4 + srow_in;           // 0..31
            int v = sslot ^ (row & 15);
            int high = v >> 3, dsl = (v & 7) * 8;
            gl_lds16(Kq + (size_t)(j0 + high * 32 + row) * 3072 + dsl, &Kt[buf][chunk * 512]);
            gl_lds16(Vbase + (size_t)(high * 32 + row) * 2048 + j0 + dsl, &Vt[buf][chunk * 512]);
        }
    };

    f32x16 o[2] = {};
    f32x16 osum = {};
    const u16x8 onesf = {0x3F80, 0x3F80, 0x3F80, 0x3F80, 0x3F80, 0x3F80, 0x3F80, 0x3F80};

    stage(0, 0);
    __syncthreads();
    int cur = 0;

    for (int t = 0; t < 32; ++t) {
        if (t < 31) stage(cur ^ 1, (t + 1) * 64);

        // ---- QK^T: S^T[j][q] in log2 units ----
        f32x16 sacc[2] = {};
        __builtin_amdgcn_s_setprio(1);
        #pragma unroll
        for (int jb = 0; jb < 2; ++jb) {
            u16x8 kf[4];
            #pragma unroll
            for (int kk = 0; kk < 4; ++kk) {
                int s = (jb * 8 + kk * 2 + hi) ^ (lq & 15);
                kf[kk] = *(const u16x8*)&Kt[cur][lq * 128 + s * 8];
            }
            #pragma unroll
            for (int kk = 0; kk < 4; ++kk)
                sacc[jb] = mfma32(kf[kk], qf[kk], sacc[jb]);
        }
        __builtin_amdgcn_s_setprio(0);

        // ---- p = 2^s, pack to bf16 pairs ----
        unsigned int pk[16];
        #pragma unroll
        for (int jb = 0; jb < 2; ++jb)
            #pragma unroll
            for (int i = 0; i < 8; ++i)
                pk[jb * 8 + i] = cvt_pk_bf16(fexp2(sacc[jb][2 * i]), fexp2(sacc[jb][2 * i + 1]));

        // ---- PV + ones-MFMA row sums ----
        #pragma unroll
        for (int kk = 0; kk < 4; ++kk) {
            const int base = (kk >> 1) * 8 + (kk & 1) * 4;
            unsigned int a0 = pk[base + 0], a1 = pk[base + 1], a2 = pk[base + 2], a3 = pk[base + 3];
            unsigned int sa0 = __shfl_xor(a0, 32), sa1 = __shfl_xor(a1, 32);
            unsigned int sa2 = __shfl_xor(a2, 32), sa3 = __shfl_xor(a3, 32);
            u32x4 w0;
            w0[0] = hib ? sa2 : a0;  w0[1] = hib ? sa3 : a1;
            w0[2] = hib ? a2 : sa0;  w0[3] = hib ? a3 : sa1;
            u16x8 pa = __builtin_bit_cast(u16x8, w0);
            __builtin_amdgcn_s_setprio(1);
            osum = mfma32(pa, onesf, osum);
            #pragma unroll
            for (int db = 0; db < 2; ++db) {
                int s = (db * 8 + kk * 2 + hi) ^ (lq & 15);
                u16x8 vf = *(const u16x8*)&Vt[cur][lq * 128 + s * 8];
                o[db] = mfma32(pa, vf, o[db]);
            }
            __builtin_amdgcn_s_setprio(0);
        }

        __syncthreads();
        cur ^= 1;
    }

    // ---- epilogue: normalize and store ----
    #pragma unroll
    for (int r = 0; r < 16; ++r) {
        int qrow = (r & 3) + 8 * (r >> 2) + 4 * hi;
        float invr = frcp(osum[r]);
        size_t ro = (size_t)(b * 2048 + q0 + qrow) * 1024 + h * 64;
        attn[ro + lq]      = f2bf(o[0][r] * invr);
        attn[ro + 32 + lq] = f2bf(o[1][r] * invr);
    }
}

extern "C" void kernel_launch(void* const* d_in, const int* in_sizes, int n_in,
                              void* d_out, int out_size, void* d_ws, size_t ws_size,
                              hipStream_t stream) {
    const float* x     = (const float*)d_in[0];
    const float* w_qkv = (const float*)d_in[1];
    const float* w_out = (const float*)d_in[2];
    const float* b_out = (const float*)d_in[3];
    float* out = (float*)d_out;

    char* ws = (char*)d_ws;
    size_t off = 0;
    auto alloc = [&](size_t bytes) -> void* {
        void* p = ws + off;
        off += (bytes + 255) & ~(size_t)255;
        return p;
    };
    unsigned short* xb    = (unsigned short*)alloc(8192ull * 1024 * 2);  // x bf16; reused as attn-out
    unsigned short* wqkvT = (unsigned short*)alloc(3072ull * 1024 * 2);
    unsigned short* woutT = (unsigned short*)alloc(1024ull * 1024 * 2);
    unsigned short* qkv   = (unsigned short*)alloc(8192ull * 3072 * 2);
    unsigned short* VTs   = (unsigned short*)alloc(64ull * 2048 * 64 * 2);
    if (off > ws_size) return;

    // scale = 0.125 * log2(e), folded into Q columns of wqkvT
    k_cvt<<<2048, 256, 0, stream>>>(x, xb, 8192 * 1024 / 4);
    k_transpose_sc<<<dim3(3072 / 32, 1024 / 32), dim3(32, 8), 0, stream>>>(
        w_qkv, wqkvT, 1024, 3072, 1024, 0.18033688f);
    k_transpose_sc<<<dim3(1024 / 32, 1024 / 32), dim3(32, 8), 0, stream>>>(
        w_out, woutT, 1024, 1024, 0, 1.0f);
    k_gemm1<<<dim3(24, 32), 512, 0, stream>>>(xb, wqkvT, qkv);
    k_vtrans<<<dim3(64, 128), dim3(32, 8), 0, stream>>>(qkv, VTs);
    k_attn<<<dim3(16, 64), 256, 0, stream>>>(qkv, VTs, xb);
    k_gemm2<<<dim3(8, 32), 512, 0, stream>>>(xb, woutT, b_out, out);
}

// Round 11
// 194.007 us; speedup vs baseline: 1.2866x; 1.0497x over previous
//
#include <hip/hip_runtime.h>
#include <hip/hip_bf16.h>

// Problem: x[4,2048,1024] f32; w_qkv[1024,3072]; w_out[1024,1024]; b_out[1024]
// out[4,2048,1024] f32.  HEADS=16, DH=64, scale=0.125 (x log2e folded into wqkvT).

typedef __attribute__((ext_vector_type(4))) float f32x4;
typedef __attribute__((ext_vector_type(16))) float f32x16;
typedef __attribute__((ext_vector_type(8))) unsigned short u16x8;
typedef __attribute__((ext_vector_type(4))) unsigned short u16x4;
typedef __attribute__((ext_vector_type(4))) unsigned int u32x4;
typedef __attribute__((ext_vector_type(8))) __bf16 bf16x8;

static __device__ __forceinline__ f32x4 mfma_bf16(u16x8 a, u16x8 b, f32x4 c) {
    return __builtin_amdgcn_mfma_f32_16x16x32_bf16(
        __builtin_bit_cast(bf16x8, a), __builtin_bit_cast(bf16x8, b), c, 0, 0, 0);
}
static __device__ __forceinline__ f32x16 mfma32(u16x8 a, u16x8 b, f32x16 c) {
    return __builtin_amdgcn_mfma_f32_32x32x16_bf16(
        __builtin_bit_cast(bf16x8, a), __builtin_bit_cast(bf16x8, b), c, 0, 0, 0);
}

static __device__ __forceinline__ unsigned short f2bf(float f) {
    unsigned int u = __builtin_bit_cast(unsigned int, f);
    u += 0x7fffu + ((u >> 16) & 1u);   // RNE
    return (unsigned short)(u >> 16);
}
static __device__ __forceinline__ unsigned int cvt_pk_bf16(float a, float b) {
    unsigned int r;
    asm("v_cvt_pk_bf16_f32 %0, %1, %2" : "=v"(r) : "v"(a), "v"(b));
    return r;
}
static __device__ __forceinline__ float fexp2(float x) {   // D = 2^S0
    float r;
    asm("v_exp_f32 %0, %1" : "=v"(r) : "v"(x));
    return r;
}
static __device__ __forceinline__ float frcp(float x) {
    float r;
    asm("v_rcp_f32 %0, %1" : "=v"(r) : "v"(x));
    return r;
}
typedef const __attribute__((address_space(1))) unsigned int* gp1_t;
typedef __attribute__((address_space(3))) unsigned int* lp3_t;
static __device__ __forceinline__ void gl_lds16(const void* g, void* l) {
    __builtin_amdgcn_global_load_lds((gp1_t)g, (lp3_t)l, 16, 0, 0);
}

// ---------------- convert x (f32 -> bf16), vectorized ----------------
__global__ void k_cvt(const float* __restrict__ in, unsigned short* __restrict__ out, int n4) {
    int i = blockIdx.x * blockDim.x + threadIdx.x;
    int stride = gridDim.x * blockDim.x;
    for (; i < n4; i += stride) {
        f32x4 v = ((const f32x4*)in)[i];
        u16x4 o;
        #pragma unroll
        for (int j = 0; j < 4; ++j) o[j] = f2bf(v[j]);
        ((u16x4*)out)[i] = o;
    }
}

// ---- transpose f32 [R][C] -> bf16 [C][R]; rows < scale_rows get *scale ----
__global__ void k_transpose_sc(const float* __restrict__ in, unsigned short* __restrict__ out,
                               int R, int C, int scale_rows, float scale) {
    __shared__ float tile[32][33];
    int c0 = blockIdx.x * 32, r0 = blockIdx.y * 32;
    int tx = threadIdx.x, ty = threadIdx.y;   // block (32,8)
    #pragma unroll
    for (int i = ty; i < 32; i += 8)
        tile[i][tx] = in[(size_t)(r0 + i) * C + c0 + tx];
    __syncthreads();
    #pragma unroll
    for (int i = ty; i < 32; i += 8) {
        float v = tile[tx][i];
        if (c0 + i < scale_rows) v *= scale;
        out[(size_t)(c0 + i) * R + r0 + tx] = f2bf(v);
    }
}

// ---------------- GEMM1 (QKV): xb[8192][1024] @ wqkvT[3072][1024] -> qkv bf16 ----
// gemm2 structure. XCD map: each XCD owns a 4-row A-band (2MB, L2-resident
// across its whole run) and walks B in chunks of 3 panels (0.75MB) -> working
// set 2.75MB < 4MB L2; B streamed once per XCD.
__global__ __launch_bounds__(512, 1) void k_gemm1(
    const unsigned short* __restrict__ A,
    const unsigned short* __restrict__ BT,
    unsigned short* __restrict__ qkv)
{
    __shared__ unsigned short As[3][256 * 64];
    __shared__ unsigned short Bs[3][128 * 64];
    const int K = 1024;
    const int tid = threadIdx.x, lane = tid & 63, wave = tid >> 6;

    // grid (24,32) = 768 = 32 by x 24 bx
    int lin = blockIdx.y * 24 + blockIdx.x;
    int xcd = lin & 7, idx = lin >> 3;        // idx 0..95
    int chunk = idx / 12, c = idx % 12;       // 8 chunks of (4 by x 3 bx)
    int by = xcd * 4 + (c / 3);
    int bx = chunk * 3 + (c % 3);
    const int m0 = by * 256, n0 = bx * 128;

    const int wm = (wave >> 1) * 64, wn = (wave & 1) * 64;
    const int lr = lane & 15, half = lane >> 4;
    const int srow = lane >> 3, sslot = lane & 7;

    auto stage_sub = [&](int buf, int t, int h) {
        int k0 = t * 64;
        #pragma unroll
        for (int r = 0; r < 2; ++r) {
            int chunkc = (h * 2 + r) * 8 + wave;
            int row = chunkc * 8 + srow;
            int koff = (sslot ^ (row & 7)) * 8;
            gl_lds16(&A[(size_t)(m0 + row) * K + k0 + koff], &As[buf][chunkc * 512]);
        }
        {
            int chunkc = h * 8 + wave;
            int row = chunkc * 8 + srow;
            int koff = (sslot ^ (row & 7)) * 8;
            gl_lds16(&BT[(size_t)(n0 + row) * K + k0 + koff], &Bs[buf][chunkc * 512]);
        }
    };

    f32x4 acc[4][4] = {};

    stage_sub(0, 0, 0); stage_sub(0, 0, 1);
    stage_sub(1, 1, 0); stage_sub(1, 1, 1);
    asm volatile("s_waitcnt vmcnt(6)" ::: "memory");
    __builtin_amdgcn_s_barrier();

    for (int t = 0; t < 16; ++t) {
        const int cur = t % 3, nxt = (t + 2) % 3;
        const bool do_stage = (t + 2) < 16;
        const unsigned short* Ab = As[cur];
        const unsigned short* Bb = Bs[cur];

        #pragma unroll
        for (int ks = 0; ks < 2; ++ks) {
            u16x8 af[4], bfr[4];
            #pragma unroll
            for (int i = 0; i < 4; ++i) {
                int ra = wm + i * 16 + lr;
                af[i] = *(const u16x8*)&Ab[ra * 64 + (((ks * 4 + half) ^ (ra & 7)) * 8)];
                int rb = wn + i * 16 + lr;
                bfr[i] = *(const u16x8*)&Bb[rb * 64 + (((ks * 4 + half) ^ (rb & 7)) * 8)];
            }
            if (do_stage) stage_sub(nxt, t + 2, ks);
            if (ks == 1) {
                if (t < 14)       asm volatile("s_waitcnt vmcnt(6)" ::: "memory");
                else if (t == 14) asm volatile("s_waitcnt vmcnt(0)" ::: "memory");
            }
            __builtin_amdgcn_s_barrier();
            asm volatile("s_waitcnt lgkmcnt(0)" ::: "memory");
            __builtin_amdgcn_sched_barrier(0);
            __builtin_amdgcn_s_setprio(1);
            #pragma unroll
            for (int i = 0; i < 4; ++i)
                #pragma unroll
                for (int j = 0; j < 4; ++j)
                    acc[i][j] = mfma_bf16(af[i], bfr[j], acc[i][j]);
            __builtin_amdgcn_s_setprio(0);
            __builtin_amdgcn_s_barrier();
        }
    }

    #pragma unroll
    for (int i = 0; i < 4; ++i)
        #pragma unroll
        for (int j = 0; j < 4; ++j)
            #pragma unroll
            for (int r = 0; r < 4; ++r) {
                int row = m0 + wm + i * 16 + half * 4 + r;
                int col = n0 + wn + j * 16 + lr;
                qkv[(size_t)row * 3072 + col] = f2bf(acc[i][j][r]);
            }
}

// ---------------- V transpose: qkv V-part -> VTs[bh][64 d][2048 n] bf16 ------
__global__ void k_vtrans(const unsigned short* __restrict__ qkv,
                         unsigned short* __restrict__ VTs) {
    __shared__ unsigned short tile[32][33];
    int bh = blockIdx.y >> 1, dt = blockIdx.y & 1;
    int b = bh >> 4, h = bh & 15;
    int n0 = blockIdx.x * 32, d0 = dt * 32;
    int tx = threadIdx.x, ty = threadIdx.y;   // block (32,8)
    const unsigned short* src = qkv + (size_t)(b * 2048) * 3072 + 2048 + h * 64 + d0;
    #pragma unroll
    for (int i = ty; i < 32; i += 8)
        tile[i][tx] = src[(size_t)(n0 + i) * 3072 + tx];
    __syncthreads();
    #pragma unroll
    for (int i = ty; i < 32; i += 8)
        VTs[((size_t)bh * 64 + d0 + i) * 2048 + n0 + tx] = tile[tx][i];
}

// ---------------- GEMM2 (out-proj): attn[8192][1024] @ woutT, +bias -> f32 ----
__global__ __launch_bounds__(512, 1) void k_gemm2(
    const unsigned short* __restrict__ A,
    const unsigned short* __restrict__ BT,
    const float* __restrict__ bias,
    float* __restrict__ outf)
{
    __shared__ unsigned short As[3][256 * 64];
    __shared__ unsigned short Bs[3][128 * 64];
    const int K = 1024;
    const int tid = threadIdx.x, lane = tid & 63, wave = tid >> 6;

    int gx = gridDim.x;
    int nwg = gx * gridDim.y;
    int lin = blockIdx.y * gx + blockIdx.x;
    int virt = (lin & 7) * (nwg >> 3) + (lin >> 3);
    int bx = virt % gx, by = virt / gx;
    const int m0 = by * 256, n0 = bx * 128;

    const int wm = (wave >> 1) * 64, wn = (wave & 1) * 64;
    const int lr = lane & 15, half = lane >> 4;
    const int srow = lane >> 3, sslot = lane & 7;

    auto stage_sub = [&](int buf, int t, int h) {
        int k0 = t * 64;
        #pragma unroll
        for (int r = 0; r < 2; ++r) {
            int chunk = (h * 2 + r) * 8 + wave;
            int row = chunk * 8 + srow;
            int koff = (sslot ^ (row & 7)) * 8;
            gl_lds16(&A[(size_t)(m0 + row) * K + k0 + koff], &As[buf][chunk * 512]);
        }
        {
            int chunk = h * 8 + wave;
            int row = chunk * 8 + srow;
            int koff = (sslot ^ (row & 7)) * 8;
            gl_lds16(&BT[(size_t)(n0 + row) * K + k0 + koff], &Bs[buf][chunk * 512]);
        }
    };

    f32x4 acc[4][4] = {};

    stage_sub(0, 0, 0); stage_sub(0, 0, 1);
    stage_sub(1, 1, 0); stage_sub(1, 1, 1);
    asm volatile("s_waitcnt vmcnt(6)" ::: "memory");
    __builtin_amdgcn_s_barrier();

    for (int t = 0; t < 16; ++t) {
        const int cur = t % 3, nxt = (t + 2) % 3;
        const bool do_stage = (t + 2) < 16;
        const unsigned short* Ab = As[cur];
        const unsigned short* Bb = Bs[cur];

        #pragma unroll
        for (int ks = 0; ks < 2; ++ks) {
            u16x8 af[4], bfr[4];
            #pragma unroll
            for (int i = 0; i < 4; ++i) {
                int ra = wm + i * 16 + lr;
                af[i] = *(const u16x8*)&Ab[ra * 64 + (((ks * 4 + half) ^ (ra & 7)) * 8)];
                int rb = wn + i * 16 + lr;
                bfr[i] = *(const u16x8*)&Bb[rb * 64 + (((ks * 4 + half) ^ (rb & 7)) * 8)];
            }
            if (do_stage) stage_sub(nxt, t + 2, ks);
            if (ks == 1) {
                if (t < 14)       asm volatile("s_waitcnt vmcnt(6)" ::: "memory");
                else if (t == 14) asm volatile("s_waitcnt vmcnt(0)" ::: "memory");
            }
            __builtin_amdgcn_s_barrier();
            asm volatile("s_waitcnt lgkmcnt(0)" ::: "memory");
            __builtin_amdgcn_sched_barrier(0);
            __builtin_amdgcn_s_setprio(1);
            #pragma unroll
            for (int i = 0; i < 4; ++i)
                #pragma unroll
                for (int j = 0; j < 4; ++j)
                    acc[i][j] = mfma_bf16(af[i], bfr[j], acc[i][j]);
            __builtin_amdgcn_s_setprio(0);
            __builtin_amdgcn_s_barrier();
        }
    }

    #pragma unroll
    for (int i = 0; i < 4; ++i)
        #pragma unroll
        for (int j = 0; j < 4; ++j)
            #pragma unroll
            for (int r = 0; r < 4; ++r) {
                int row = m0 + wm + i * 16 + half * 4 + r;
                int col = n0 + wn + j * 16 + lr;
                outf[(size_t)row * 1024 + col] = acc[i][j][r] + bias[col];
            }
}

// ---------------- flash attention: swapped-QK 32x32, 1 q-block/wave ---------
// grid (16,64), 4 blocks/CU. P-fragment assembly via v_permlane32_swap_b32:
// swap(a0,a2) -> {a0_lo,a2_lo},{a0_hi,a2_hi} = exactly the lo/hi PA words,
// replacing 4 ds_bpermute (shfl) + 4 cndmask per pair with 1 VALU op.
__global__ __launch_bounds__(256, 4) void k_attn(
    const unsigned short* __restrict__ qkv,
    const unsigned short* __restrict__ VTs,
    unsigned short* __restrict__ attn)   // [8192][1024] bf16
{
    __shared__ unsigned short Kt[2][64 * 64];
    __shared__ unsigned short Vt[2][64 * 64];
    const int tid = threadIdx.x, lane = tid & 63, wave = tid >> 6;

    int lin = blockIdx.y * 16 + blockIdx.x;   // 1024 wgs, bijective XCD map
    int virt = (lin & 7) * 128 + (lin >> 3);
    int bh = virt >> 4;
    int q0 = (virt & 15) * 128 + wave * 32;

    const int lq = lane & 31;
    const int hi = lane >> 5;

    int b = bh >> 4, h = bh & 15;
    const unsigned short* Kq = qkv + (size_t)(b * 2048) * 3072 + 1024 + h * 64;
    const unsigned short* Vbase = VTs + (size_t)bh * 64 * 2048;

    u16x8 qf[4];
    {
        const unsigned short* Qr = qkv + (size_t)(b * 2048 + q0 + lq) * 3072 + h * 64;
        #pragma unroll
        for (int kk = 0; kk < 4; ++kk)
            qf[kk] = *(const u16x8*)&Qr[kk * 16 + hi * 8];
    }

    const int srow_in = lane >> 4, sslot = lane & 15;
    auto stage = [&](int buf, int j0) {
        #pragma unroll
        for (int c = 0; c < 2; ++c) {
            int chunk = wave * 2 + c;
            int row = chunk * 4 + srow_in;           // 0..31
            int v = sslot ^ (row & 15);
            int high = v >> 3, dsl = (v & 7) * 8;
            gl_lds16(Kq + (size_t)(j0 + high * 32 + row) * 3072 + dsl, &Kt[buf][chunk * 512]);
            gl_lds16(Vbase + (size_t)(high * 32 + row) * 2048 + j0 + dsl, &Vt[buf][chunk * 512]);
        }
    };

    f32x16 o[2] = {};
    f32x16 osum = {};
    const u16x8 onesf = {0x3F80, 0x3F80, 0x3F80, 0x3F80, 0x3F80, 0x3F80, 0x3F80, 0x3F80};

    stage(0, 0);
    __syncthreads();
    int cur = 0;

    for (int t = 0; t < 32; ++t) {
        if (t < 31) stage(cur ^ 1, (t + 1) * 64);

        // ---- QK^T: S^T[j][q] in log2 units ----
        f32x16 sacc[2] = {};
        __builtin_amdgcn_s_setprio(1);
        #pragma unroll
        for (int jb = 0; jb < 2; ++jb) {
            u16x8 kf[4];
            #pragma unroll
            for (int kk = 0; kk < 4; ++kk) {
                int s = (jb * 8 + kk * 2 + hi) ^ (lq & 15);
                kf[kk] = *(const u16x8*)&Kt[cur][lq * 128 + s * 8];
            }
            #pragma unroll
            for (int kk = 0; kk < 4; ++kk)
                sacc[jb] = mfma32(kf[kk], qf[kk], sacc[jb]);
        }
        __builtin_amdgcn_s_setprio(0);

        // ---- p = 2^s, pack to bf16 pairs ----
        unsigned int pk[16];
        #pragma unroll
        for (int jb = 0; jb < 2; ++jb)
            #pragma unroll
            for (int i = 0; i < 8; ++i)
                pk[jb * 8 + i] = cvt_pk_bf16(fexp2(sacc[jb][2 * i]), fexp2(sacc[jb][2 * i + 1]));

        // ---- PV + ones-MFMA row sums (permlane32_swap fragment assembly) ----
        __builtin_amdgcn_s_setprio(1);
        #pragma unroll
        for (int kk = 0; kk < 4; ++kk) {
            const int base = (kk >> 1) * 8 + (kk & 1) * 4;
            unsigned int w0 = pk[base + 0], w2 = pk[base + 2];
            unsigned int w1 = pk[base + 1], w3 = pk[base + 3];
            asm("v_permlane32_swap_b32 %0, %1" : "+v"(w0), "+v"(w2));
            asm("v_permlane32_swap_b32 %0, %1" : "+v"(w1), "+v"(w3));
            u32x4 w; w[0] = w0; w[1] = w1; w[2] = w2; w[3] = w3;
            u16x8 pa = __builtin_bit_cast(u16x8, w);
            osum = mfma32(pa, onesf, osum);
            #pragma unroll
            for (int db = 0; db < 2; ++db) {
                int s = (db * 8 + kk * 2 + hi) ^ (lq & 15);
                u16x8 vf = *(const u16x8*)&Vt[cur][lq * 128 + s * 8];
                o[db] = mfma32(pa, vf, o[db]);
            }
        }
        __builtin_amdgcn_s_setprio(0);

        __syncthreads();
        cur ^= 1;
    }

    // ---- epilogue: normalize and store ----
    #pragma unroll
    for (int r = 0; r < 16; ++r) {
        int qrow = (r & 3) + 8 * (r >> 2) + 4 * hi;
        float invr = frcp(osum[r]);
        size_t ro = (size_t)(b * 2048 + q0 + qrow) * 1024 + h * 64;
        attn[ro + lq]      = f2bf(o[0][r] * invr);
        attn[ro + 32 + lq] = f2bf(o[1][r] * invr);
    }
}

extern "C" void kernel_launch(void* const* d_in, const int* in_sizes, int n_in,
                              void* d_out, int out_size, void* d_ws, size_t ws_size,
                              hipStream_t stream) {
    const float* x     = (const float*)d_in[0];
    const float* w_qkv = (const float*)d_in[1];
    const float* w_out = (const float*)d_in[2];
    const float* b_out = (const float*)d_in[3];
    float* out = (float*)d_out;

    char* ws = (char*)d_ws;
    size_t off = 0;
    auto alloc = [&](size_t bytes) -> void* {
        void* p = ws + off;
        off += (bytes + 255) & ~(size_t)255;
        return p;
    };
    unsigned short* xb    = (unsigned short*)alloc(8192ull * 1024 * 2);  // x bf16; reused as attn-out
    unsigned short* wqkvT = (unsigned short*)alloc(3072ull * 1024 * 2);
    unsigned short* woutT = (unsigned short*)alloc(1024ull * 1024 * 2);
    unsigned short* qkv   = (unsigned short*)alloc(8192ull * 3072 * 2);
    unsigned short* VTs   = (unsigned short*)alloc(64ull * 2048 * 64 * 2);
    if (off > ws_size) return;

    // scale = 0.125 * log2(e), folded into Q columns of wqkvT
    k_cvt<<<2048, 256, 0, stream>>>(x, xb, 8192 * 1024 / 4);
    k_transpose_sc<<<dim3(3072 / 32, 1024 / 32), dim3(32, 8), 0, stream>>>(
        w_qkv, wqkvT, 1024, 3072, 1024, 0.18033688f);
    k_transpose_sc<<<dim3(1024 / 32, 1024 / 32), dim3(32, 8), 0, stream>>>(
        w_out, woutT, 1024, 1024, 0, 1.0f);
    k_gemm1<<<dim3(24, 32), 512, 0, stream>>>(xb, wqkvT, qkv);
    k_vtrans<<<dim3(64, 128), dim3(32, 8), 0, stream>>>(qkv, VTs);
    k_attn<<<dim3(16, 64), 256, 0, stream>>>(qkv, VTs, xb);
    k_gemm2<<<dim3(8, 32), 512, 0, stream>>>(xb, woutT, b_out, out);
}